// Round 2
// baseline (876731.836 us; speedup 1.0000x reference)
//
#include <hip/hip_runtime.h>
#include <hip/hip_bf16.h>
#include <math.h>

// Problem constants
#define H   512
#define E   512
#define B_  256
#define T_  64
#define G4  2048   // 4*H
#define C1  256    // MLP hidden
#define BT  16384  // B*T

#define SPIN_CAP (1 << 22)   // discovery spin bound (dispatch latency)
#define POLL_CAP (1 << 18)   // per-step poll bound: ~33ms worst case ->
                             // visibility bug = fast wrong answer, not hang

typedef __attribute__((ext_vector_type(8))) short  short8;   // 8 bf16 (4 VGPRs)
typedef __attribute__((ext_vector_type(4))) float  f32x4;    // MFMA acc
typedef __attribute__((ext_vector_type(4))) int    i32x4;    // 16B granule
typedef __attribute__((ext_vector_type(4))) unsigned short ushort4v;
typedef unsigned short ushort;
typedef unsigned long long u64;

// LDS tile: row-major [row][kc granule], pitch 65 granules (odd) = 520 ushorts.
// Write wave (per quarter-wave: row fixed, 16 consecutive gc): granule mod 8
// hits each residue 2x -> canonical-linear, conflict-free. Read wave (kk
// fixed, quarter-wave = quad): granule = 65*l16 + 4kk + quad -> same.
#define PITCH_US 520

#define BAR_LGKM() asm volatile("s_waitcnt lgkmcnt(0)\n\ts_barrier" ::: "memory")
#define BAR_ALL()  asm volatile("s_waitcnt vmcnt(0) lgkmcnt(0)\n\ts_barrier" ::: "memory")

__device__ __forceinline__ ushort f2bf(float x) {
    unsigned u = __builtin_bit_cast(unsigned, x);
    unsigned r = (u + 0x7FFFu + ((u >> 16) & 1u)) >> 16;
    return (ushort)r;
}
__device__ __forceinline__ float fast_sig(float x) {
    return __builtin_amdgcn_rcpf(1.f + __expf(-x));
}
__device__ __forceinline__ float fast_tanh(float x) {
    return 1.f - 2.f * __builtin_amdgcn_rcpf(1.f + __expf(2.f * x));
}

// Local-XCD L2 atomic add (no sc1): RMW resolves in this XCD's L2.
// Only valid when every reader/writer of the line is on the same XCD
// (loc teams). Fire-and-forget; drained by the next BAR_ALL.
__device__ __forceinline__ void atom_add_l2(int* p, int v) {
    asm volatile("global_atomic_add %0, %1, off" :: "v"(p), "v"(v) : "memory");
}
// Local-XCD L2 load (sc0: L1-bypass, reads this XCD's L2 where the
// local atomic landed). ~200cy vs ~500-700cy for the MALL path.
__device__ __forceinline__ int load_l2(const int* p) {
    int v;
    asm volatile("global_load_dword %0, %1, off sc0\n\ts_waitcnt vmcnt(0)"
                 : "=v"(v) : "v"(p) : "memory");
    return v;
}

// 4x 16B loads, batched, drained. sc0: L1-bypass, local XCD L2 (R8-proven).
#define LOAD4_SC0(v0,v1,v2,v3,p0,p1,p2,p3) \
  asm volatile("global_load_dwordx4 %0, %4, off sc0\n\t" \
               "global_load_dwordx4 %1, %5, off sc0\n\t" \
               "global_load_dwordx4 %2, %6, off sc0\n\t" \
               "global_load_dwordx4 %3, %7, off sc0\n\t" \
               "s_waitcnt vmcnt(0)" \
               : "=&v"(v0), "=&v"(v1), "=&v"(v2), "=&v"(v3) \
               : "v"(p0), "v"(p1), "v"(p2), "v"(p3) : "memory")
// sc0 sc1: device-coherent (MALL) — cross-XCD fallback (R5/R8-proven).
#define LOAD4_SC01(v0,v1,v2,v3,p0,p1,p2,p3) \
  asm volatile("global_load_dwordx4 %0, %4, off sc0 sc1\n\t" \
               "global_load_dwordx4 %1, %5, off sc0 sc1\n\t" \
               "global_load_dwordx4 %2, %6, off sc0 sc1\n\t" \
               "global_load_dwordx4 %3, %7, off sc0 sc1\n\t" \
               "s_waitcnt vmcnt(0)" \
               : "=&v"(v0), "=&v"(v1), "=&v"(v2), "=&v"(v3) \
               : "v"(p0), "v"(p1), "v"(p2), "v"(p3) : "memory")

// ---------------------------------------------------------------------------
// P0: fused weight prep — transpose + cast fp32 [K][N] -> bf16 [N][K]
// blocks 0..1023: Wx (512x2048); 1024..2047: Wh; 2048..2303: W1 (1024x256)
// ---------------------------------------------------------------------------
__global__ __launch_bounds__(256) void prep_weights(
    const float* __restrict__ Wx, const float* __restrict__ Wh,
    const float* __restrict__ W1,
    ushort* __restrict__ WxT, ushort* __restrict__ WhT, ushort* __restrict__ W1T)
{
    __shared__ float t[32][33];
    int bx = blockIdx.x;
    const float* in; ushort* out; int K, N, k0, n0;
    if (bx < 1024)       { in = Wx; out = WxT; K = 512;  N = 2048; k0 = (bx >> 6) * 32; n0 = (bx & 63) * 32; }
    else if (bx < 2048)  { bx -= 1024; in = Wh; out = WhT; K = 512;  N = 2048; k0 = (bx >> 6) * 32; n0 = (bx & 63) * 32; }
    else                 { bx -= 2048; in = W1; out = W1T; K = 1024; N = 256;  k0 = (bx >> 3) * 32; n0 = (bx & 7) * 32; }
    const int tr = threadIdx.x >> 3;
    const int tc = (threadIdx.x & 7) * 4;
    float4 v = *(const float4*)(in + (size_t)(k0 + tr) * N + n0 + tc);
    t[tr][tc + 0] = v.x; t[tr][tc + 1] = v.y; t[tr][tc + 2] = v.z; t[tr][tc + 3] = v.w;
    __syncthreads();
    ushort4v o = { f2bf(t[tc + 0][tr]), f2bf(t[tc + 1][tr]),
                   f2bf(t[tc + 2][tr]), f2bf(t[tc + 3][tr]) };
    *(ushort4v*)(out + (size_t)(n0 + tr) * K + k0 + tc) = o;
}

// ---------------------------------------------------------------------------
// P1: gather X[r,:] = bf16(choice_embed[arg_seq[r], :])
// ---------------------------------------------------------------------------
__global__ __launch_bounds__(128) void gather_embed_bf16(
    const float* __restrict__ emb, const int* __restrict__ idx,
    ushort* __restrict__ X)
{
    const int r = blockIdx.x;
    const int v = idx[r];
    const int c = threadIdx.x * 4;
    float4 f = *(const float4*)(emb + (size_t)v * E + c);
    ushort4v o = { f2bf(f.x), f2bf(f.y), f2bf(f.z), f2bf(f.w) };
    *(ushort4v*)(X + (size_t)r * E + c) = o;
}

// ---------------------------------------------------------------------------
// P2: h0 (bf16) and S[:,0,:] (bf16) from init_state
// ---------------------------------------------------------------------------
__global__ __launch_bounds__(128) void init_prep(
    const float* __restrict__ init, ushort* __restrict__ h0,
    ushort* __restrict__ S)
{
    const int r = blockIdx.x;
    const int c = threadIdx.x * 4;
    float4 f = *(const float4*)(init + (size_t)r * H + c);
    ushort4v o = { f2bf(f.x), f2bf(f.y), f2bf(f.z), f2bf(f.w) };
    *(ushort4v*)(h0 + (size_t)r * H + c) = o;
    *(ushort4v*)(S + ((size_t)r * T_) * H + c) = o;
}

// ---------------------------------------------------------------------------
// P3: zero scores + xcd table + counters (contiguous region)
// ---------------------------------------------------------------------------
__global__ __launch_bounds__(256) void zero_buf(int* p, int n) {
    int i = blockIdx.x * 256 + threadIdx.x;
    if (i < n) p[i] = 0;
}

// ---------------------------------------------------------------------------
// K2: persistent fused LSTM recurrence + fused x@Wx.
// 256 blocks, 1/CU. XCD discovery -> 16-block XCD-local teams where dispatch
// allows. Signal: ONE cumulative counter per team. For XCD-local teams the
// counter lives in the LOCAL XCD L2: plain global_atomic_add (no sc1) to
// signal, sc0 loads to poll — cuts the per-step MALL round trip (~500-700cy
// each way) to a local L2 hit (~200cy). Non-local fallback: device-scope
// atomicAdd + AGENT relaxed poll (R5/R8-proven). h data: sc0 local-L2 for
// local teams, sc0sc1 fallback (R8-proven). S store after the signal (off
// the drain path). LDS: row-major odd-pitch tiles, conflict-free both ways.
// ---------------------------------------------------------------------------
__global__ __launch_bounds__(256, 1) void lstm_fused_main(
    const ushort* __restrict__ WhT, const ushort* __restrict__ WxT,
    const ushort* __restrict__ Xbf, const float* __restrict__ bg,
    const float*  __restrict__ init_state, const ushort* __restrict__ h0,
    ushort* __restrict__ pp0, ushort* __restrict__ pp1,
    ushort* __restrict__ S, int* __restrict__ xcd_tbl, int* __restrict__ cnts)
{
    __shared__ __align__(16) ushort hsh[16 * PITCH_US];
    __shared__ __align__(16) ushort xsh[2][16 * PITCH_US];
    __shared__ int exl[256];

    const int tid  = threadIdx.x;
    const int wave = tid >> 6, lane = tid & 63;
    const int quad = lane >> 4, l16 = lane & 15;

    // ---- one-time team discovery (bounded) ----
    int xcd;
    asm volatile("s_getreg_b32 %0, hwreg(HW_REG_XCC_ID)" : "=s"(xcd));
    if (tid == 0)
        __hip_atomic_store(&xcd_tbl[blockIdx.x], (xcd & 7) + 1,
                           __ATOMIC_RELAXED, __HIP_MEMORY_SCOPE_AGENT);
    if (wave == 0) {
        for (int it = 0; it < SPIN_CAP; ++it) {
            int miss = 0;
#pragma unroll
            for (int j = 0; j < 4; ++j) {
                int i = lane + j * 64;
                int v = __hip_atomic_load(&xcd_tbl[i], __ATOMIC_RELAXED,
                                          __HIP_MEMORY_SCOPE_AGENT);
                exl[i] = (v == 0) ? 0 : (v - 1);
                if (v == 0) miss = 1;
            }
            if (!__any(miss)) break;
            __builtin_amdgcn_s_sleep(4);
        }
    }
    BAR_LGKM();

    // deterministic assignment (identical scan in every thread)
    int g = 0, m = 0, loc = 0;
    {
        int cntx[8] = {0,0,0,0,0,0,0,0};
        for (int i = 0; i < 256; ++i) cntx[exl[i] & 7]++;
        int take[8], base[8], tA = 0;
        for (int x = 0; x < 8; ++x) {
            int tk = cntx[x] >> 4;
            if (tA + tk > 16) tk = 16 - tA;
            take[x] = tk; base[x] = tA; tA += tk;
        }
        int rc[8] = {0,0,0,0,0,0,0,0}, lc = 0;
        for (int i = 0; i < 256; ++i) {
            int x = exl[i] & 7, r = rc[x]++;
            if ((r >> 4) < take[x]) {
                if (i == (int)blockIdx.x) { g = base[x] + (r >> 4); m = r & 15; loc = 1; }
            } else {
                if (i == (int)blockIdx.x) { g = tA + (lc >> 4); m = lc & 15; loc = 0; }
                lc++;
            }
        }
    }

    const int n0   = g * 16;
    const int jw   = m * 32 + wave * 8;
    const int koff = quad * 8;
    const int ccol = jw + (quad & 1) * 4;
    const int myrow = n0 + l16;

    // A-frag preloads: Wh and Wx (layout validated rounds 2-8)
    short8 af[2][16], ax[2][16];
#pragma unroll
    for (int mf = 0; mf < 2; ++mf) {
        const int gate = mf * 2 + (l16 >> 3);
        const size_t rowoff = (size_t)(gate * 512 + jw + (l16 & 7)) * 512 + koff;
        const ushort* bh = WhT + rowoff;
        const ushort* bx = WxT + rowoff;
#pragma unroll
        for (int kk = 0; kk < 16; ++kk) {
            af[mf][kk] = *(const short8*)(bh + kk * 32);
            ax[mf][kk] = *(const short8*)(bx + kk * 32);
        }
    }

    // bias preload
    float bgi[4], bgf[4], bgg[4], bgo[4];
#pragma unroll
    for (int r = 0; r < 4; ++r) {
        bgi[r] = bg[ccol + r];
        bgf[r] = bg[512 + ccol + r];
        bgg[r] = bg[1024 + ccol + r];
        bgo[r] = bg[1536 + ccol + r];
    }

    // c-state init
    float c[4];
    {
        const float* ip = init_state + (size_t)myrow * H + ccol;
#pragma unroll
        for (int r = 0; r < 4; ++r) c[r] = ip[r];
    }

    // staging coords: 4 granules of 16B per thread; row-major pitch-520 tile
    int gr[4], gc[4], lo[4];
#pragma unroll
    for (int j = 0; j < 4; ++j) {
        int lin = tid + j * 256;
        gr[j] = lin >> 6; gc[j] = lin & 63;
        lo[j] = gr[j] * PITCH_US + gc[j] * 8;
    }

    // stage x(0) into xsh[0]
#pragma unroll
    for (int j = 0; j < 4; ++j) {
        i32x4 v = *(const i32x4*)(Xbf + ((size_t)(n0 + gr[j]) * T_) * H + gc[j] * 8);
        *(i32x4*)&xsh[0][lo[j]] = v;
    }
    BAR_LGKM();

    int* cnt = cnts + g * 32;                          // 128B apart per team
    const int frag_base = l16 * PITCH_US + quad * 8;   // + kk*32

    for (int t = 0; t < T_ - 1; ++t) {
        // a) issue x(t+1) prefetch (plain cached loads)
        i32x4 xv0, xv1, xv2, xv3;
        const int have_x = (t + 1 < T_ - 1);
        if (have_x) {
            xv0 = *(const i32x4*)(Xbf + ((size_t)(n0 + gr[0]) * T_ + t + 1) * H + gc[0] * 8);
            xv1 = *(const i32x4*)(Xbf + ((size_t)(n0 + gr[1]) * T_ + t + 1) * H + gc[1] * 8);
            xv2 = *(const i32x4*)(Xbf + ((size_t)(n0 + gr[2]) * T_ + t + 1) * H + gc[2] * 8);
            xv3 = *(const i32x4*)(Xbf + ((size_t)(n0 + gr[3]) * T_ + t + 1) * H + gc[3] * 8);
        }

        // b) x-part MFMA (independent of h -> overlaps the wait)
        f32x4 ax0 = {}, ax1 = {};
        {
            const ushort* xb = xsh[t & 1];
#pragma unroll
            for (int kk = 0; kk < 16; ++kk) {
                short8 b = *(const short8*)&xb[frag_base + kk * 32];
                ax0 = __builtin_amdgcn_mfma_f32_16x16x32_bf16(ax[0][kk], b, ax0, 0, 0, 0);
                ax1 = __builtin_amdgcn_mfma_f32_16x16x32_bf16(ax[1][kk], b, ax1, 0, 0, 0);
            }
        }

        // c) wait for teammates' h(t): every wave polls the team counter.
        //    loc teams: sc0 load hits the LOCAL XCD L2 (where the local
        //    atomic landed) — ~200cy/poll instead of a MALL round trip.
        if (t > 0) {
            const int tgt = t << 4;
            if (loc) {
                for (int it = 0; it < POLL_CAP; ++it) {
                    if (load_l2(cnt) >= tgt) break;
                    __builtin_amdgcn_s_sleep(1);
                }
            } else {
                for (int it = 0; it < POLL_CAP; ++it) {
                    if (__hip_atomic_load(cnt, __ATOMIC_RELAXED,
                                          __HIP_MEMORY_SCOPE_AGENT) >= tgt) break;
                    __builtin_amdgcn_s_sleep(1);
                }
            }
        }

        // d) stage h(t) into LDS (16B loads; local L2 for loc teams)
        {
            const ushort* hin = (t == 0) ? h0 : ((t & 1) ? pp0 : pp1);
            const ushort* p0 = hin + (size_t)(n0 + gr[0]) * H + gc[0] * 8;
            const ushort* p1 = hin + (size_t)(n0 + gr[1]) * H + gc[1] * 8;
            const ushort* p2 = hin + (size_t)(n0 + gr[2]) * H + gc[2] * 8;
            const ushort* p3 = hin + (size_t)(n0 + gr[3]) * H + gc[3] * 8;
            i32x4 v0, v1, v2, v3;
            if (loc) { LOAD4_SC0(v0, v1, v2, v3, p0, p1, p2, p3); }
            else     { LOAD4_SC01(v0, v1, v2, v3, p0, p1, p2, p3); }
            *(i32x4*)&hsh[lo[0]] = v0;
            *(i32x4*)&hsh[lo[1]] = v1;
            *(i32x4*)&hsh[lo[2]] = v2;
            *(i32x4*)&hsh[lo[3]] = v3;
        }
        BAR_LGKM();

        // e) h-part MFMA
        f32x4 a0 = {}, a1 = {};
#pragma unroll
        for (int kk = 0; kk < 16; ++kk) {
            short8 b = *(const short8*)&hsh[frag_base + kk * 32];
            a0 = __builtin_amdgcn_mfma_f32_16x16x32_bf16(af[0][kk], b, a0, 0, 0, 0);
            a1 = __builtin_amdgcn_mfma_f32_16x16x32_bf16(af[1][kk], b, a1, 0, 0, 0);
        }

        // f) write x(t+1) into the other xsh buffer
        if (have_x) {
            ushort* xb = xsh[(t + 1) & 1];
            *(i32x4*)&xb[lo[0]] = xv0;
            *(i32x4*)&xb[lo[1]] = xv1;
            *(i32x4*)&xb[lo[2]] = xv2;
            *(i32x4*)&xb[lo[3]] = xv3;
        }

        // g) epilogue: combine, activate, update c
        float hv[4];
#pragma unroll
        for (int r = 0; r < 4; ++r) {
            float v0 = a0[r] + ax0[r], v1 = a1[r] + ax1[r];
            float p0 = __shfl_xor(v0, 32, 64);
            float p1 = __shfl_xor(v1, 32, 64);
            float iv = (quad < 2) ? v0 : p0;
            float fv = (quad < 2) ? p0 : v0;
            float gv = (quad < 2) ? v1 : p1;
            float ov = (quad < 2) ? p1 : v1;
            iv = fast_sig(iv + bgi[r]);
            fv = fast_sig(fv + bgf[r]);
            gv = fast_tanh(gv + bgg[r]);
            ov = fast_sig(ov + bgo[r]);
            float cn = fv * c[r] + iv * gv;
            c[r] = cn;
            hv[r] = ov * fast_tanh(cn);
        }

        // h) h store (exchange buffer) — the only VMEM outstanding at drain
        ushort4v o4 = { f2bf(hv[0]), f2bf(hv[1]), f2bf(hv[2]), f2bf(hv[3]) };
        ushort* hout = (t & 1) ? pp1 : pp0;
        if (quad < 2) {
            u64* hp = (u64*)(hout + (size_t)myrow * H + ccol);
            if (loc) *hp = __builtin_bit_cast(u64, o4);
            else __hip_atomic_store(hp, __builtin_bit_cast(u64, o4),
                                    __ATOMIC_RELAXED, __HIP_MEMORY_SCOPE_AGENT);
        }

        // i) drain h store, block barrier, signal. loc teams: local-L2
        //    atomic (no sc1) — the h stores are already in this same L2,
        //    so the signal is ordered-after by the vmcnt(0) drain.
        BAR_ALL();
        if (tid == 0) {
            if (loc) atom_add_l2(cnt, 1);
            else     atomicAdd(cnt, 1);
        }

        // j) S store AFTER the signal — drained by a later vmcnt(0)
        if (quad < 2)
            *(ushort4v*)(S + ((size_t)myrow * T_ + (t + 1)) * H + ccol) = o4;
    }
}

// ---------------------------------------------------------------------------
// K3: phase C fused with score head.
// hid = relu(S@W1a^T + X@W1b^T + b1) in-register; score[row] += hid.W2 via
// shfl-reduce + atomicAdd. hid never materialized.
// ---------------------------------------------------------------------------
__global__ __launch_bounds__(256) void gemm_score(
    const ushort* __restrict__ Sm, const ushort* __restrict__ Xbf,
    const ushort* __restrict__ W1T,   // [256][1024]
    const float* __restrict__ b1, const float* __restrict__ W2,
    float* __restrict__ scores)
{
    const int tid  = threadIdx.x;
    const int wave = tid >> 6, lane = tid & 63;
    const int quad = lane >> 4, l16 = lane & 15;
    const int m0 = blockIdx.y * 128 + wave * 32;
    const int n0 = blockIdx.x * 64;
    const int koff = quad * 8;

    f32x4 acc[2][4] = {};

    for (int src = 0; src < 2; ++src) {
        const ushort* A  = src ? Xbf : Sm;
        const ushort* Bm = W1T + src * 512;
        const ushort* a0p = A + (size_t)(m0 + l16) * H + koff;
        const ushort* a1p = A + (size_t)(m0 + 16 + l16) * H + koff;
        const ushort* bp  = Bm + (size_t)(n0 + l16) * 1024 + koff;
        for (int kk = 0; kk < H; kk += 32) {
            short8 a0 = *(const short8*)(a0p + kk);
            short8 a1 = *(const short8*)(a1p + kk);
#pragma unroll
            for (int nf = 0; nf < 4; ++nf) {
                short8 b = *(const short8*)(bp + (size_t)nf * 16 * 1024 + kk);
                acc[0][nf] = __builtin_amdgcn_mfma_f32_16x16x32_bf16(a0, b, acc[0][nf], 0, 0, 0);
                acc[1][nf] = __builtin_amdgcn_mfma_f32_16x16x32_bf16(a1, b, acc[1][nf], 0, 0, 0);
            }
        }
    }

    float w2v[4], b1v[4];
#pragma unroll
    for (int nf = 0; nf < 4; ++nf) {
        const int col = n0 + nf * 16 + l16;
        w2v[nf] = W2[col];
        b1v[nf] = b1[col];
    }

#pragma unroll
    for (int mf = 0; mf < 2; ++mf) {
#pragma unroll
        for (int r = 0; r < 4; ++r) {
            float p = 0.f;
#pragma unroll
            for (int nf = 0; nf < 4; ++nf)
                p += fmaxf(acc[mf][nf][r] + b1v[nf], 0.f) * w2v[nf];
            p += __shfl_xor(p, 1, 64);
            p += __shfl_xor(p, 2, 64);
            p += __shfl_xor(p, 4, 64);
            p += __shfl_xor(p, 8, 64);
            if (l16 == 0)
                atomicAdd(&scores[m0 + mf * 16 + quad * 4 + r], p);
        }
    }
}

// ---------------------------------------------------------------------------
// K4: out[b] = sum_t (scores[b*T+t] + b2)
// ---------------------------------------------------------------------------
__global__ __launch_bounds__(64) void reduce_scores(
    const float* __restrict__ scores, const float* __restrict__ b2,
    float* __restrict__ out)
{
    const int b    = blockIdx.x;
    const int lane = threadIdx.x;
    float s = scores[(size_t)b * T_ + lane] + b2[0];
#pragma unroll
    for (int off = 32; off; off >>= 1) s += __shfl_xor(s, off, 64);
    if (lane == 0) out[b] = s;
}

// ---------------------------------------------------------------------------
extern "C" void kernel_launch(void* const* d_in, const int* in_sizes, int n_in,
                              void* d_out, int out_size, void* d_ws, size_t ws_size,
                              hipStream_t stream)
{
    const float* init_state = (const float*)d_in[0];
    const float* choice_emb = (const float*)d_in[1];
    const int*   arg_seq    = (const int*)  d_in[2];
    const float* Wx         = (const float*)d_in[3];
    const float* Wh         = (const float*)d_in[4];
    const float* bg         = (const float*)d_in[5];
    const float* W1         = (const float*)d_in[6];
    const float* b1         = (const float*)d_in[7];
    const float* W2         = (const float*)d_in[8];
    const float* b2         = (const float*)d_in[9];
    float* out = (float*)d_out;

    // workspace layout
    ushort* WxT = (ushort*)d_ws;                 // [2048,512] bf16
    ushort* WhT = WxT + 1048576;                 // [2048,512] bf16
    ushort* W1T = WhT + 1048576;                 // [256,1024] bf16
    ushort* Xbf = W1T + 262144;                  // [BT,512]  bf16
    ushort* S   = Xbf + 8388608;                 // [B,T,H]   bf16
    ushort* h0  = S   + 8388608;                 // [B,H]
    ushort* pp0 = h0  + 131072;                  // [B,H]
    ushort* pp1 = pp0 + 131072;                  // [B,H]
    float*  scores  = (float*)(pp1 + 131072);    // [BT]
    int*    xcd_tbl = (int*)(scores + BT);       // [256]
    int*    cnts    = xcd_tbl + 256;             // [16*32]

    // zero scores + table + counters (contiguous ints)
    zero_buf<<<70, 256, 0, stream>>>((int*)scores, BT + 256 + 512);

    // fused weight prep (Wx, Wh, W1 in one launch)
    prep_weights<<<2304, 256, 0, stream>>>(Wx, Wh, W1, WxT, WhT, W1T);

    // embedding gather -> bf16; state init
    gather_embed_bf16<<<BT, 128, 0, stream>>>(choice_emb, arg_seq, Xbf);
    init_prep<<<B_, 128, 0, stream>>>(init_state, h0, S);

    // Phase A+B fused: persistent recurrence with in-kernel x@Wx
    lstm_fused_main<<<256, 256, 0, stream>>>(
        WhT, WxT, Xbf, bg, init_state, h0, pp0, pp1, S, xcd_tbl, cnts);

    // Phase C+D fused: score accumulation
    gemm_score<<<dim3(C1 / 64, BT / 128), 256, 0, stream>>>(
        S, Xbf, W1T, b1, W2, scores);
    reduce_scores<<<B_, 64, 0, stream>>>(scores, b2, out);
}

// Round 3
// 391486.108 us; speedup vs baseline: 2.2395x; 2.2395x over previous
//
#include <hip/hip_runtime.h>
#include <hip/hip_bf16.h>
#include <math.h>

// Problem constants
#define H   512
#define E   512
#define B_  256
#define T_  64
#define G4  2048   // 4*H
#define C1  256    // MLP hidden
#define BT  16384  // B*T

#define SPIN_CAP (1 << 22)   // discovery spin bound (dispatch latency)
#define POLL_CAP (1 << 18)   // per-step poll bound: visibility bug -> slow-but-
                             // correct run with counters, not a hang (R2-proven)

typedef __attribute__((ext_vector_type(8))) short  short8;   // 8 bf16 (4 VGPRs)
typedef __attribute__((ext_vector_type(4))) float  f32x4;    // MFMA acc
typedef __attribute__((ext_vector_type(4))) int    i32x4;    // 16B granule
typedef __attribute__((ext_vector_type(4))) unsigned short ushort4v;
typedef unsigned short ushort;
typedef unsigned long long u64;

// LDS tile: row-major [row][kc granule], pitch 65 granules (odd) = 520 ushorts.
#define PITCH_US 520

#define BAR_LGKM() asm volatile("s_waitcnt lgkmcnt(0)\n\ts_barrier" ::: "memory")
#define BAR_ALL()  asm volatile("s_waitcnt vmcnt(0) lgkmcnt(0)\n\ts_barrier" ::: "memory")

__device__ __forceinline__ ushort f2bf(float x) {
    unsigned u = __builtin_bit_cast(unsigned, x);
    unsigned r = (u + 0x7FFFu + ((u >> 16) & 1u)) >> 16;
    return (ushort)r;
}
__device__ __forceinline__ float fast_sig(float x) {
    return __builtin_amdgcn_rcpf(1.f + __expf(-x));
}
__device__ __forceinline__ float fast_tanh(float x) {
    return 1.f - 2.f * __builtin_amdgcn_rcpf(1.f + __expf(2.f * x));
}

// Per-lane local-XCD L2 load (sc0: L1-bypass, reads the XCD L2 where
// teammates' plain stores land — the R8-proven data-visibility path).
// R2 ERRATA: unflagged global_atomic_add is NOT visible to sc0 loads
// (atomics bypass L2 to the MALL without invalidating clean L2 lines).
// Signals therefore use plain stores + this load, never atomics.
__device__ __forceinline__ int load_slot_l2(const int* p) {
    int v;
    asm volatile("global_load_dword %0, %1, off sc0\n\ts_waitcnt vmcnt(0)"
                 : "=v"(v) : "v"(p) : "memory");
    return v;
}

// 4x 16B loads, batched, drained. sc0: L1-bypass, local XCD L2 (R8-proven).
#define LOAD4_SC0(v0,v1,v2,v3,p0,p1,p2,p3) \
  asm volatile("global_load_dwordx4 %0, %4, off sc0\n\t" \
               "global_load_dwordx4 %1, %5, off sc0\n\t" \
               "global_load_dwordx4 %2, %6, off sc0\n\t" \
               "global_load_dwordx4 %3, %7, off sc0\n\t" \
               "s_waitcnt vmcnt(0)" \
               : "=&v"(v0), "=&v"(v1), "=&v"(v2), "=&v"(v3) \
               : "v"(p0), "v"(p1), "v"(p2), "v"(p3) : "memory")
// sc0 sc1: device-coherent (MALL) — cross-XCD fallback (R5/R8-proven).
#define LOAD4_SC01(v0,v1,v2,v3,p0,p1,p2,p3) \
  asm volatile("global_load_dwordx4 %0, %4, off sc0 sc1\n\t" \
               "global_load_dwordx4 %1, %5, off sc0 sc1\n\t" \
               "global_load_dwordx4 %2, %6, off sc0 sc1\n\t" \
               "global_load_dwordx4 %3, %7, off sc0 sc1\n\t" \
               "s_waitcnt vmcnt(0)" \
               : "=&v"(v0), "=&v"(v1), "=&v"(v2), "=&v"(v3) \
               : "v"(p0), "v"(p1), "v"(p2), "v"(p3) : "memory")

// ---------------------------------------------------------------------------
// P0: fused weight prep — transpose + cast fp32 [K][N] -> bf16 [N][K]
// ---------------------------------------------------------------------------
__global__ __launch_bounds__(256) void prep_weights(
    const float* __restrict__ Wx, const float* __restrict__ Wh,
    const float* __restrict__ W1,
    ushort* __restrict__ WxT, ushort* __restrict__ WhT, ushort* __restrict__ W1T)
{
    __shared__ float t[32][33];
    int bx = blockIdx.x;
    const float* in; ushort* out; int K, N, k0, n0;
    if (bx < 1024)       { in = Wx; out = WxT; K = 512;  N = 2048; k0 = (bx >> 6) * 32; n0 = (bx & 63) * 32; }
    else if (bx < 2048)  { bx -= 1024; in = Wh; out = WhT; K = 512;  N = 2048; k0 = (bx >> 6) * 32; n0 = (bx & 63) * 32; }
    else                 { bx -= 2048; in = W1; out = W1T; K = 1024; N = 256;  k0 = (bx >> 3) * 32; n0 = (bx & 7) * 32; }
    const int tr = threadIdx.x >> 3;
    const int tc = (threadIdx.x & 7) * 4;
    float4 v = *(const float4*)(in + (size_t)(k0 + tr) * N + n0 + tc);
    t[tr][tc + 0] = v.x; t[tr][tc + 1] = v.y; t[tr][tc + 2] = v.z; t[tr][tc + 3] = v.w;
    __syncthreads();
    ushort4v o = { f2bf(t[tc + 0][tr]), f2bf(t[tc + 1][tr]),
                   f2bf(t[tc + 2][tr]), f2bf(t[tc + 3][tr]) };
    *(ushort4v*)(out + (size_t)(n0 + tr) * K + k0 + tc) = o;
}

// ---------------------------------------------------------------------------
// P1: gather X[r,:] = bf16(choice_embed[arg_seq[r], :])
// ---------------------------------------------------------------------------
__global__ __launch_bounds__(128) void gather_embed_bf16(
    const float* __restrict__ emb, const int* __restrict__ idx,
    ushort* __restrict__ X)
{
    const int r = blockIdx.x;
    const int v = idx[r];
    const int c = threadIdx.x * 4;
    float4 f = *(const float4*)(emb + (size_t)v * E + c);
    ushort4v o = { f2bf(f.x), f2bf(f.y), f2bf(f.z), f2bf(f.w) };
    *(ushort4v*)(X + (size_t)r * E + c) = o;
}

// ---------------------------------------------------------------------------
// P2: h0 (bf16) and S[:,0,:] (bf16) from init_state
// ---------------------------------------------------------------------------
__global__ __launch_bounds__(128) void init_prep(
    const float* __restrict__ init, ushort* __restrict__ h0,
    ushort* __restrict__ S)
{
    const int r = blockIdx.x;
    const int c = threadIdx.x * 4;
    float4 f = *(const float4*)(init + (size_t)r * H + c);
    ushort4v o = { f2bf(f.x), f2bf(f.y), f2bf(f.z), f2bf(f.w) };
    *(ushort4v*)(h0 + (size_t)r * H + c) = o;
    *(ushort4v*)(S + ((size_t)r * T_) * H + c) = o;
}

// ---------------------------------------------------------------------------
// P3: zero scores + xcd table + slot arrays (contiguous region)
// ---------------------------------------------------------------------------
__global__ __launch_bounds__(256) void zero_buf(int* p, int n) {
    int i = blockIdx.x * 256 + threadIdx.x;
    if (i < n) p[i] = 0;
}

// ---------------------------------------------------------------------------
// K2: persistent fused LSTM recurrence + fused x@Wx.
// 256 blocks, 1/CU. XCD discovery -> 16-block XCD-local teams where dispatch
// allows. Signal: 16-slot flag array per team; block m PLAIN-stores t+1 to
// slot m after its h(t+1) stores are drained (BAR_ALL). Pollers: lane l16
// sc0-loads slot[l16], __all(v>=t) — pure local-L2 traffic for loc teams
// (~300cy/poll vs ~650cy MALL). Non-loc fallback: AGENT-scope store/load
// (sc1, R5/R8-proven). NO atomics (R2 errata: unflagged atomics bypass L2
// and are invisible to sc0 loads). h data: sc0 local-L2 for loc teams,
// sc0sc1 fallback. S store after the signal (off the drain path).
// LDS: row-major odd-pitch tiles, conflict-free both directions.
// ---------------------------------------------------------------------------
__global__ __launch_bounds__(256, 1) void lstm_fused_main(
    const ushort* __restrict__ WhT, const ushort* __restrict__ WxT,
    const ushort* __restrict__ Xbf, const float* __restrict__ bg,
    const float*  __restrict__ init_state, const ushort* __restrict__ h0,
    ushort* __restrict__ pp0, ushort* __restrict__ pp1,
    ushort* __restrict__ S, int* __restrict__ xcd_tbl, int* __restrict__ cnts)
{
    __shared__ __align__(16) ushort hsh[16 * PITCH_US];
    __shared__ __align__(16) ushort xsh[2][16 * PITCH_US];
    __shared__ int exl[256];

    const int tid  = threadIdx.x;
    const int wave = tid >> 6, lane = tid & 63;
    const int quad = lane >> 4, l16 = lane & 15;

    // ---- one-time team discovery (bounded) ----
    int xcd;
    asm volatile("s_getreg_b32 %0, hwreg(HW_REG_XCC_ID)" : "=s"(xcd));
    if (tid == 0)
        __hip_atomic_store(&xcd_tbl[blockIdx.x], (xcd & 7) + 1,
                           __ATOMIC_RELAXED, __HIP_MEMORY_SCOPE_AGENT);
    if (wave == 0) {
        for (int it = 0; it < SPIN_CAP; ++it) {
            int miss = 0;
#pragma unroll
            for (int j = 0; j < 4; ++j) {
                int i = lane + j * 64;
                int v = __hip_atomic_load(&xcd_tbl[i], __ATOMIC_RELAXED,
                                          __HIP_MEMORY_SCOPE_AGENT);
                exl[i] = (v == 0) ? 0 : (v - 1);
                if (v == 0) miss = 1;
            }
            if (!__any(miss)) break;
            __builtin_amdgcn_s_sleep(4);
        }
    }
    BAR_LGKM();

    // deterministic assignment (identical scan in every thread)
    int g = 0, m = 0, loc = 0;
    {
        int cntx[8] = {0,0,0,0,0,0,0,0};
        for (int i = 0; i < 256; ++i) cntx[exl[i] & 7]++;
        int take[8], base[8], tA = 0;
        for (int x = 0; x < 8; ++x) {
            int tk = cntx[x] >> 4;
            if (tA + tk > 16) tk = 16 - tA;
            take[x] = tk; base[x] = tA; tA += tk;
        }
        int rc[8] = {0,0,0,0,0,0,0,0}, lc = 0;
        for (int i = 0; i < 256; ++i) {
            int x = exl[i] & 7, r = rc[x]++;
            if ((r >> 4) < take[x]) {
                if (i == (int)blockIdx.x) { g = base[x] + (r >> 4); m = r & 15; loc = 1; }
            } else {
                if (i == (int)blockIdx.x) { g = tA + (lc >> 4); m = lc & 15; loc = 0; }
                lc++;
            }
        }
    }

    const int n0   = g * 16;
    const int jw   = m * 32 + wave * 8;
    const int koff = quad * 8;
    const int ccol = jw + (quad & 1) * 4;
    const int myrow = n0 + l16;

    // A-frag preloads: Wh and Wx (layout validated rounds 2-8)
    short8 af[2][16], ax[2][16];
#pragma unroll
    for (int mf = 0; mf < 2; ++mf) {
        const int gate = mf * 2 + (l16 >> 3);
        const size_t rowoff = (size_t)(gate * 512 + jw + (l16 & 7)) * 512 + koff;
        const ushort* bh = WhT + rowoff;
        const ushort* bx = WxT + rowoff;
#pragma unroll
        for (int kk = 0; kk < 16; ++kk) {
            af[mf][kk] = *(const short8*)(bh + kk * 32);
            ax[mf][kk] = *(const short8*)(bx + kk * 32);
        }
    }

    // bias preload
    float bgi[4], bgf[4], bgg[4], bgo[4];
#pragma unroll
    for (int r = 0; r < 4; ++r) {
        bgi[r] = bg[ccol + r];
        bgf[r] = bg[512 + ccol + r];
        bgg[r] = bg[1024 + ccol + r];
        bgo[r] = bg[1536 + ccol + r];
    }

    // c-state init
    float c[4];
    {
        const float* ip = init_state + (size_t)myrow * H + ccol;
#pragma unroll
        for (int r = 0; r < 4; ++r) c[r] = ip[r];
    }

    // staging coords: 4 granules of 16B per thread; row-major pitch-520 tile
    int gr[4], gc[4], lo[4];
#pragma unroll
    for (int j = 0; j < 4; ++j) {
        int lin = tid + j * 256;
        gr[j] = lin >> 6; gc[j] = lin & 63;
        lo[j] = gr[j] * PITCH_US + gc[j] * 8;
    }

    // stage x(0) into xsh[0]
#pragma unroll
    for (int j = 0; j < 4; ++j) {
        i32x4 v = *(const i32x4*)(Xbf + ((size_t)(n0 + gr[j]) * T_) * H + gc[j] * 8);
        *(i32x4*)&xsh[0][lo[j]] = v;
    }
    BAR_LGKM();

    int* slots = cnts + g * 32;                        // 128B apart per team
    int* myslot = slots + m;
    const int* pollp = slots + l16;                    // lane-indexed slot
    const int frag_base = l16 * PITCH_US + quad * 8;   // + kk*32

    for (int t = 0; t < T_ - 1; ++t) {
        // a) issue x(t+1) prefetch (plain cached loads)
        i32x4 xv0, xv1, xv2, xv3;
        const int have_x = (t + 1 < T_ - 1);
        if (have_x) {
            xv0 = *(const i32x4*)(Xbf + ((size_t)(n0 + gr[0]) * T_ + t + 1) * H + gc[0] * 8);
            xv1 = *(const i32x4*)(Xbf + ((size_t)(n0 + gr[1]) * T_ + t + 1) * H + gc[1] * 8);
            xv2 = *(const i32x4*)(Xbf + ((size_t)(n0 + gr[2]) * T_ + t + 1) * H + gc[2] * 8);
            xv3 = *(const i32x4*)(Xbf + ((size_t)(n0 + gr[3]) * T_ + t + 1) * H + gc[3] * 8);
        }

        // b) x-part MFMA (independent of h -> overlaps the wait)
        f32x4 ax0 = {}, ax1 = {};
        {
            const ushort* xb = xsh[t & 1];
#pragma unroll
            for (int kk = 0; kk < 16; ++kk) {
                short8 b = *(const short8*)&xb[frag_base + kk * 32];
                ax0 = __builtin_amdgcn_mfma_f32_16x16x32_bf16(ax[0][kk], b, ax0, 0, 0, 0);
                ax1 = __builtin_amdgcn_mfma_f32_16x16x32_bf16(ax[1][kk], b, ax1, 0, 0, 0);
            }
        }

        // c) wait for teammates' h(t): lane l16 polls slot l16 (all 16 slots
        //    covered per wave); __all over the replicated lanes. loc teams:
        //    sc0 loads hit the local XCD L2 where the plain-store signals
        //    land — no MALL traffic on the poll at all.
        if (t > 0) {
            if (loc) {
                for (int it = 0; it < POLL_CAP; ++it) {
                    int v = load_slot_l2(pollp);
                    if (__all(v >= t)) break;
                    __builtin_amdgcn_s_sleep(1);
                }
            } else {
                for (int it = 0; it < POLL_CAP; ++it) {
                    int v = __hip_atomic_load(pollp, __ATOMIC_RELAXED,
                                              __HIP_MEMORY_SCOPE_AGENT);
                    if (__all(v >= t)) break;
                    __builtin_amdgcn_s_sleep(1);
                }
            }
        }

        // d) stage h(t) into LDS (16B loads; local L2 for loc teams)
        {
            const ushort* hin = (t == 0) ? h0 : ((t & 1) ? pp0 : pp1);
            const ushort* p0 = hin + (size_t)(n0 + gr[0]) * H + gc[0] * 8;
            const ushort* p1 = hin + (size_t)(n0 + gr[1]) * H + gc[1] * 8;
            const ushort* p2 = hin + (size_t)(n0 + gr[2]) * H + gc[2] * 8;
            const ushort* p3 = hin + (size_t)(n0 + gr[3]) * H + gc[3] * 8;
            i32x4 v0, v1, v2, v3;
            if (loc) { LOAD4_SC0(v0, v1, v2, v3, p0, p1, p2, p3); }
            else     { LOAD4_SC01(v0, v1, v2, v3, p0, p1, p2, p3); }
            *(i32x4*)&hsh[lo[0]] = v0;
            *(i32x4*)&hsh[lo[1]] = v1;
            *(i32x4*)&hsh[lo[2]] = v2;
            *(i32x4*)&hsh[lo[3]] = v3;
        }
        BAR_LGKM();

        // e) h-part MFMA
        f32x4 a0 = {}, a1 = {};
#pragma unroll
        for (int kk = 0; kk < 16; ++kk) {
            short8 b = *(const short8*)&hsh[frag_base + kk * 32];
            a0 = __builtin_amdgcn_mfma_f32_16x16x32_bf16(af[0][kk], b, a0, 0, 0, 0);
            a1 = __builtin_amdgcn_mfma_f32_16x16x32_bf16(af[1][kk], b, a1, 0, 0, 0);
        }

        // f) write x(t+1) into the other xsh buffer
        if (have_x) {
            ushort* xb = xsh[(t + 1) & 1];
            *(i32x4*)&xb[lo[0]] = xv0;
            *(i32x4*)&xb[lo[1]] = xv1;
            *(i32x4*)&xb[lo[2]] = xv2;
            *(i32x4*)&xb[lo[3]] = xv3;
        }

        // g) epilogue: combine, activate, update c
        float hv[4];
#pragma unroll
        for (int r = 0; r < 4; ++r) {
            float v0 = a0[r] + ax0[r], v1 = a1[r] + ax1[r];
            float p0 = __shfl_xor(v0, 32, 64);
            float p1 = __shfl_xor(v1, 32, 64);
            float iv = (quad < 2) ? v0 : p0;
            float fv = (quad < 2) ? p0 : v0;
            float gv = (quad < 2) ? v1 : p1;
            float ov = (quad < 2) ? p1 : v1;
            iv = fast_sig(iv + bgi[r]);
            fv = fast_sig(fv + bgf[r]);
            gv = fast_tanh(gv + bgg[r]);
            ov = fast_sig(ov + bgo[r]);
            float cn = fv * c[r] + iv * gv;
            c[r] = cn;
            hv[r] = ov * fast_tanh(cn);
        }

        // h) h store (exchange buffer) — the only VMEM outstanding at drain
        ushort4v o4 = { f2bf(hv[0]), f2bf(hv[1]), f2bf(hv[2]), f2bf(hv[3]) };
        ushort* hout = (t & 1) ? pp1 : pp0;
        if (quad < 2) {
            u64* hp = (u64*)(hout + (size_t)myrow * H + ccol);
            if (loc) *hp = __builtin_bit_cast(u64, o4);
            else __hip_atomic_store(hp, __builtin_bit_cast(u64, o4),
                                    __ATOMIC_RELAXED, __HIP_MEMORY_SCOPE_AGENT);
        }

        // i) drain h stores, block barrier, then signal slot m := t+1 via
        //    PLAIN store (loc: lands in local L2, same visibility point as
        //    the h data; non-loc: agent-scope store). Monotonic value ->
        //    no lost-wakeup; fire-and-forget, drained by next step's vmcnt.
        BAR_ALL();
        if (tid == 0) {
            if (loc) *(volatile int*)myslot = t + 1;
            else __hip_atomic_store(myslot, t + 1, __ATOMIC_RELAXED,
                                    __HIP_MEMORY_SCOPE_AGENT);
        }

        // j) S store AFTER the signal — drained by a later vmcnt(0)
        if (quad < 2)
            *(ushort4v*)(S + ((size_t)myrow * T_ + (t + 1)) * H + ccol) = o4;
    }
}

// ---------------------------------------------------------------------------
// K3: phase C fused with score head.
// ---------------------------------------------------------------------------
__global__ __launch_bounds__(256) void gemm_score(
    const ushort* __restrict__ Sm, const ushort* __restrict__ Xbf,
    const ushort* __restrict__ W1T,   // [256][1024]
    const float* __restrict__ b1, const float* __restrict__ W2,
    float* __restrict__ scores)
{
    const int tid  = threadIdx.x;
    const int wave = tid >> 6, lane = tid & 63;
    const int quad = lane >> 4, l16 = lane & 15;
    const int m0 = blockIdx.y * 128 + wave * 32;
    const int n0 = blockIdx.x * 64;
    const int koff = quad * 8;

    f32x4 acc[2][4] = {};

    for (int src = 0; src < 2; ++src) {
        const ushort* A  = src ? Xbf : Sm;
        const ushort* Bm = W1T + src * 512;
        const ushort* a0p = A + (size_t)(m0 + l16) * H + koff;
        const ushort* a1p = A + (size_t)(m0 + 16 + l16) * H + koff;
        const ushort* bp  = Bm + (size_t)(n0 + l16) * 1024 + koff;
        for (int kk = 0; kk < H; kk += 32) {
            short8 a0 = *(const short8*)(a0p + kk);
            short8 a1 = *(const short8*)(a1p + kk);
#pragma unroll
            for (int nf = 0; nf < 4; ++nf) {
                short8 b = *(const short8*)(bp + (size_t)nf * 16 * 1024 + kk);
                acc[0][nf] = __builtin_amdgcn_mfma_f32_16x16x32_bf16(a0, b, acc[0][nf], 0, 0, 0);
                acc[1][nf] = __builtin_amdgcn_mfma_f32_16x16x32_bf16(a1, b, acc[1][nf], 0, 0, 0);
            }
        }
    }

    float w2v[4], b1v[4];
#pragma unroll
    for (int nf = 0; nf < 4; ++nf) {
        const int col = n0 + nf * 16 + l16;
        w2v[nf] = W2[col];
        b1v[nf] = b1[col];
    }

#pragma unroll
    for (int mf = 0; mf < 2; ++mf) {
#pragma unroll
        for (int r = 0; r < 4; ++r) {
            float p = 0.f;
#pragma unroll
            for (int nf = 0; nf < 4; ++nf)
                p += fmaxf(acc[mf][nf][r] + b1v[nf], 0.f) * w2v[nf];
            p += __shfl_xor(p, 1, 64);
            p += __shfl_xor(p, 2, 64);
            p += __shfl_xor(p, 4, 64);
            p += __shfl_xor(p, 8, 64);
            if (l16 == 0)
                atomicAdd(&scores[m0 + mf * 16 + quad * 4 + r], p);
        }
    }
}

// ---------------------------------------------------------------------------
// K4: out[b] = sum_t (scores[b*T+t] + b2)
// ---------------------------------------------------------------------------
__global__ __launch_bounds__(64) void reduce_scores(
    const float* __restrict__ scores, const float* __restrict__ b2,
    float* __restrict__ out)
{
    const int b    = blockIdx.x;
    const int lane = threadIdx.x;
    float s = scores[(size_t)b * T_ + lane] + b2[0];
#pragma unroll
    for (int off = 32; off; off >>= 1) s += __shfl_xor(s, off, 64);
    if (lane == 0) out[b] = s;
}

// ---------------------------------------------------------------------------
extern "C" void kernel_launch(void* const* d_in, const int* in_sizes, int n_in,
                              void* d_out, int out_size, void* d_ws, size_t ws_size,
                              hipStream_t stream)
{
    const float* init_state = (const float*)d_in[0];
    const float* choice_emb = (const float*)d_in[1];
    const int*   arg_seq    = (const int*)  d_in[2];
    const float* Wx         = (const float*)d_in[3];
    const float* Wh         = (const float*)d_in[4];
    const float* bg         = (const float*)d_in[5];
    const float* W1         = (const float*)d_in[6];
    const float* b1         = (const float*)d_in[7];
    const float* W2         = (const float*)d_in[8];
    const float* b2         = (const float*)d_in[9];
    float* out = (float*)d_out;

    // workspace layout
    ushort* WxT = (ushort*)d_ws;                 // [2048,512] bf16
    ushort* WhT = WxT + 1048576;                 // [2048,512] bf16
    ushort* W1T = WhT + 1048576;                 // [256,1024] bf16
    ushort* Xbf = W1T + 262144;                  // [BT,512]  bf16
    ushort* S   = Xbf + 8388608;                 // [B,T,H]   bf16
    ushort* h0  = S   + 8388608;                 // [B,H]
    ushort* pp0 = h0  + 131072;                  // [B,H]
    ushort* pp1 = pp0 + 131072;                  // [B,H]
    float*  scores  = (float*)(pp1 + 131072);    // [BT]
    int*    xcd_tbl = (int*)(scores + BT);       // [256]
    int*    cnts    = xcd_tbl + 256;             // [16*32] slot arrays

    // zero scores + table + slots (contiguous ints)
    zero_buf<<<70, 256, 0, stream>>>((int*)scores, BT + 256 + 512);

    // fused weight prep (Wx, Wh, W1 in one launch)
    prep_weights<<<2304, 256, 0, stream>>>(Wx, Wh, W1, WxT, WhT, W1T);

    // embedding gather -> bf16; state init
    gather_embed_bf16<<<BT, 128, 0, stream>>>(choice_emb, arg_seq, Xbf);
    init_prep<<<B_, 128, 0, stream>>>(init_state, h0, S);

    // Phase A+B fused: persistent recurrence with in-kernel x@Wx
    lstm_fused_main<<<256, 256, 0, stream>>>(
        WhT, WxT, Xbf, bg, init_state, h0, pp0, pp1, S, xcd_tbl, cnts);

    // Phase C+D fused: score accumulation
    gemm_score<<<dim3(C1 / 64, BT / 128), 256, 0, stream>>>(
        S, Xbf, W1T, b1, W2, scores);
    reduce_scores<<<B_, 64, 0, stream>>>(scores, b2, out);
}

// Round 4
// 947.839 us; speedup vs baseline: 924.9799x; 413.0303x over previous
//
#include <hip/hip_runtime.h>
#include <hip/hip_bf16.h>
#include <math.h>

// Problem constants
#define H   512
#define E   512
#define B_  256
#define T_  64
#define G4  2048   // 4*H
#define C1  256    // MLP hidden
#define BT  16384  // B*T

#define SPIN_CAP (1 << 22)   // discovery spin bound (dispatch latency)
#define POLL_CAP (1 << 18)   // agent-poll bound (fallback path)
#define PH1_CAP  128         // sc0 local-L2 poll attempts before MALL fallback

typedef __attribute__((ext_vector_type(8))) short  short8;   // 8 bf16 (4 VGPRs)
typedef __attribute__((ext_vector_type(4))) float  f32x4;    // MFMA acc
typedef __attribute__((ext_vector_type(4))) int    i32x4;    // 16B granule
typedef __attribute__((ext_vector_type(4))) unsigned short ushort4v;
typedef unsigned short ushort;
typedef unsigned long long u64;

// LDS tile: row-major [row][kc granule], pitch 65 granules (odd) = 520 ushorts.
#define PITCH_US 520

#define BAR_LGKM() asm volatile("s_waitcnt lgkmcnt(0)\n\ts_barrier" ::: "memory")
#define BAR_ALL()  asm volatile("s_waitcnt vmcnt(0) lgkmcnt(0)\n\ts_barrier" ::: "memory")

__device__ __forceinline__ ushort f2bf(float x) {
    unsigned u = __builtin_bit_cast(unsigned, x);
    unsigned r = (u + 0x7FFFu + ((u >> 16) & 1u)) >> 16;
    return (ushort)r;
}
__device__ __forceinline__ float fast_sig(float x) {
    return __builtin_amdgcn_rcpf(1.f + __expf(-x));
}
__device__ __forceinline__ float fast_tanh(float x) {
    return 1.f - 2.f * __builtin_amdgcn_rcpf(1.f + __expf(2.f * x));
}

// Visibility ledger (R2/R3 errata, R8-proven data path):
//   plain store        -> updates local XCD L2   -> sc0 load SEES it
//   unflagged atomic   -> RMW at MALL, L2 stale  -> sc0 load NEVER sees it (R2)
//   volatile store     -> compiler emits sc0 sc1 -> bypasses L2 to MALL,
//                         L2 clean line stale    -> sc0 load NEVER sees it (R3)
// Therefore the loc-team signal uses a PLAIN unflagged store via inline asm
// (same instruction class as the proven h-data store), and the poller's
// phase-1 reads it with sc0. Phase-2 fallback + non-loc path go through the
// MALL with agent-scope ops (R0-proven pairing).
__device__ __forceinline__ void store_slot_plain(int* p, int v) {
    asm volatile("global_store_dword %0, %1, off" :: "v"(p), "v"(v) : "memory");
}
__device__ __forceinline__ int load_slot_l2(const int* p) {
    int v;
    asm volatile("global_load_dword %0, %1, off sc0\n\ts_waitcnt vmcnt(0)"
                 : "=v"(v) : "v"(p) : "memory");
    return v;
}

// 4x 16B loads, batched, drained. sc0: L1-bypass, local XCD L2 (R8-proven).
#define LOAD4_SC0(v0,v1,v2,v3,p0,p1,p2,p3) \
  asm volatile("global_load_dwordx4 %0, %4, off sc0\n\t" \
               "global_load_dwordx4 %1, %5, off sc0\n\t" \
               "global_load_dwordx4 %2, %6, off sc0\n\t" \
               "global_load_dwordx4 %3, %7, off sc0\n\t" \
               "s_waitcnt vmcnt(0)" \
               : "=&v"(v0), "=&v"(v1), "=&v"(v2), "=&v"(v3) \
               : "v"(p0), "v"(p1), "v"(p2), "v"(p3) : "memory")
// sc0 sc1: device-coherent (MALL) — cross-XCD fallback (R5/R8-proven).
#define LOAD4_SC01(v0,v1,v2,v3,p0,p1,p2,p3) \
  asm volatile("global_load_dwordx4 %0, %4, off sc0 sc1\n\t" \
               "global_load_dwordx4 %1, %5, off sc0 sc1\n\t" \
               "global_load_dwordx4 %2, %6, off sc0 sc1\n\t" \
               "global_load_dwordx4 %3, %7, off sc0 sc1\n\t" \
               "s_waitcnt vmcnt(0)" \
               : "=&v"(v0), "=&v"(v1), "=&v"(v2), "=&v"(v3) \
               : "v"(p0), "v"(p1), "v"(p2), "v"(p3) : "memory")

// ---------------------------------------------------------------------------
// P0: fused weight prep — transpose + cast fp32 [K][N] -> bf16 [N][K]
// ---------------------------------------------------------------------------
__global__ __launch_bounds__(256) void prep_weights(
    const float* __restrict__ Wx, const float* __restrict__ Wh,
    const float* __restrict__ W1,
    ushort* __restrict__ WxT, ushort* __restrict__ WhT, ushort* __restrict__ W1T)
{
    __shared__ float t[32][33];
    int bx = blockIdx.x;
    const float* in; ushort* out; int K, N, k0, n0;
    if (bx < 1024)       { in = Wx; out = WxT; K = 512;  N = 2048; k0 = (bx >> 6) * 32; n0 = (bx & 63) * 32; }
    else if (bx < 2048)  { bx -= 1024; in = Wh; out = WhT; K = 512;  N = 2048; k0 = (bx >> 6) * 32; n0 = (bx & 63) * 32; }
    else                 { bx -= 2048; in = W1; out = W1T; K = 1024; N = 256;  k0 = (bx >> 3) * 32; n0 = (bx & 7) * 32; }
    const int tr = threadIdx.x >> 3;
    const int tc = (threadIdx.x & 7) * 4;
    float4 v = *(const float4*)(in + (size_t)(k0 + tr) * N + n0 + tc);
    t[tr][tc + 0] = v.x; t[tr][tc + 1] = v.y; t[tr][tc + 2] = v.z; t[tr][tc + 3] = v.w;
    __syncthreads();
    ushort4v o = { f2bf(t[tc + 0][tr]), f2bf(t[tc + 1][tr]),
                   f2bf(t[tc + 2][tr]), f2bf(t[tc + 3][tr]) };
    *(ushort4v*)(out + (size_t)(n0 + tr) * K + k0 + tc) = o;
}

// ---------------------------------------------------------------------------
// P1: gather X[r,:] = bf16(choice_embed[arg_seq[r], :])
// ---------------------------------------------------------------------------
__global__ __launch_bounds__(128) void gather_embed_bf16(
    const float* __restrict__ emb, const int* __restrict__ idx,
    ushort* __restrict__ X)
{
    const int r = blockIdx.x;
    const int v = idx[r];
    const int c = threadIdx.x * 4;
    float4 f = *(const float4*)(emb + (size_t)v * E + c);
    ushort4v o = { f2bf(f.x), f2bf(f.y), f2bf(f.z), f2bf(f.w) };
    *(ushort4v*)(X + (size_t)r * E + c) = o;
}

// ---------------------------------------------------------------------------
// P2: h0 (bf16) and S[:,0,:] (bf16) from init_state
// ---------------------------------------------------------------------------
__global__ __launch_bounds__(128) void init_prep(
    const float* __restrict__ init, ushort* __restrict__ h0,
    ushort* __restrict__ S)
{
    const int r = blockIdx.x;
    const int c = threadIdx.x * 4;
    float4 f = *(const float4*)(init + (size_t)r * H + c);
    ushort4v o = { f2bf(f.x), f2bf(f.y), f2bf(f.z), f2bf(f.w) };
    *(ushort4v*)(h0 + (size_t)r * H + c) = o;
    *(ushort4v*)(S + ((size_t)r * T_) * H + c) = o;
}

// ---------------------------------------------------------------------------
// P3: zero scores + xcd table + slot arrays (contiguous region)
// ---------------------------------------------------------------------------
__global__ __launch_bounds__(256) void zero_buf(int* p, int n) {
    int i = blockIdx.x * 256 + threadIdx.x;
    if (i < n) p[i] = 0;
}

// ---------------------------------------------------------------------------
// K2: persistent fused LSTM recurrence + fused x@Wx.
// 256 blocks, 1/CU. XCD discovery -> 16-block XCD-local teams where dispatch
// allows. Signal: 16-slot flag array per team; block m stores t+1 to slot m
// after its h(t+1) stores are drained (BAR_ALL). loc teams: PLAIN unflagged
// store (lands in local L2 — the only primitive proven visible to sc0
// loads; R2/R3 errata) + trailing agent store as MALL safety net. Poll:
// lane l16 reads slot l16, __all(v>=t); phase-1 = PH1_CAP sc0 polls
// (local L2, ~300cy detect), phase-2 = agent polls (MALL, R0-proven).
// h data: sc0 local-L2 for loc teams, sc0sc1 fallback (R8-proven).
// S store after the signal (off the drain path). LDS: row-major odd-pitch
// tiles, conflict-free both directions.
// ---------------------------------------------------------------------------
__global__ __launch_bounds__(256, 1) void lstm_fused_main(
    const ushort* __restrict__ WhT, const ushort* __restrict__ WxT,
    const ushort* __restrict__ Xbf, const float* __restrict__ bg,
    const float*  __restrict__ init_state, const ushort* __restrict__ h0,
    ushort* __restrict__ pp0, ushort* __restrict__ pp1,
    ushort* __restrict__ S, int* __restrict__ xcd_tbl, int* __restrict__ cnts)
{
    __shared__ __align__(16) ushort hsh[16 * PITCH_US];
    __shared__ __align__(16) ushort xsh[2][16 * PITCH_US];
    __shared__ int exl[256];

    const int tid  = threadIdx.x;
    const int wave = tid >> 6, lane = tid & 63;
    const int quad = lane >> 4, l16 = lane & 15;

    // ---- one-time team discovery (bounded) ----
    int xcd;
    asm volatile("s_getreg_b32 %0, hwreg(HW_REG_XCC_ID)" : "=s"(xcd));
    if (tid == 0)
        __hip_atomic_store(&xcd_tbl[blockIdx.x], (xcd & 7) + 1,
                           __ATOMIC_RELAXED, __HIP_MEMORY_SCOPE_AGENT);
    if (wave == 0) {
        for (int it = 0; it < SPIN_CAP; ++it) {
            int miss = 0;
#pragma unroll
            for (int j = 0; j < 4; ++j) {
                int i = lane + j * 64;
                int v = __hip_atomic_load(&xcd_tbl[i], __ATOMIC_RELAXED,
                                          __HIP_MEMORY_SCOPE_AGENT);
                exl[i] = (v == 0) ? 0 : (v - 1);
                if (v == 0) miss = 1;
            }
            if (!__any(miss)) break;
            __builtin_amdgcn_s_sleep(4);
        }
    }
    BAR_LGKM();

    // deterministic assignment (identical scan in every thread)
    int g = 0, m = 0, loc = 0;
    {
        int cntx[8] = {0,0,0,0,0,0,0,0};
        for (int i = 0; i < 256; ++i) cntx[exl[i] & 7]++;
        int take[8], base[8], tA = 0;
        for (int x = 0; x < 8; ++x) {
            int tk = cntx[x] >> 4;
            if (tA + tk > 16) tk = 16 - tA;
            take[x] = tk; base[x] = tA; tA += tk;
        }
        int rc[8] = {0,0,0,0,0,0,0,0}, lc = 0;
        for (int i = 0; i < 256; ++i) {
            int x = exl[i] & 7, r = rc[x]++;
            if ((r >> 4) < take[x]) {
                if (i == (int)blockIdx.x) { g = base[x] + (r >> 4); m = r & 15; loc = 1; }
            } else {
                if (i == (int)blockIdx.x) { g = tA + (lc >> 4); m = lc & 15; loc = 0; }
                lc++;
            }
        }
    }

    const int n0   = g * 16;
    const int jw   = m * 32 + wave * 8;
    const int koff = quad * 8;
    const int ccol = jw + (quad & 1) * 4;
    const int myrow = n0 + l16;

    // A-frag preloads: Wh and Wx (layout validated rounds 2-8)
    short8 af[2][16], ax[2][16];
#pragma unroll
    for (int mf = 0; mf < 2; ++mf) {
        const int gate = mf * 2 + (l16 >> 3);
        const size_t rowoff = (size_t)(gate * 512 + jw + (l16 & 7)) * 512 + koff;
        const ushort* bh = WhT + rowoff;
        const ushort* bx = WxT + rowoff;
#pragma unroll
        for (int kk = 0; kk < 16; ++kk) {
            af[mf][kk] = *(const short8*)(bh + kk * 32);
            ax[mf][kk] = *(const short8*)(bx + kk * 32);
        }
    }

    // bias preload
    float bgi[4], bgf[4], bgg[4], bgo[4];
#pragma unroll
    for (int r = 0; r < 4; ++r) {
        bgi[r] = bg[ccol + r];
        bgf[r] = bg[512 + ccol + r];
        bgg[r] = bg[1024 + ccol + r];
        bgo[r] = bg[1536 + ccol + r];
    }

    // c-state init
    float c[4];
    {
        const float* ip = init_state + (size_t)myrow * H + ccol;
#pragma unroll
        for (int r = 0; r < 4; ++r) c[r] = ip[r];
    }

    // staging coords: 4 granules of 16B per thread; row-major pitch-520 tile
    int gr[4], gc[4], lo[4];
#pragma unroll
    for (int j = 0; j < 4; ++j) {
        int lin = tid + j * 256;
        gr[j] = lin >> 6; gc[j] = lin & 63;
        lo[j] = gr[j] * PITCH_US + gc[j] * 8;
    }

    // stage x(0) into xsh[0]
#pragma unroll
    for (int j = 0; j < 4; ++j) {
        i32x4 v = *(const i32x4*)(Xbf + ((size_t)(n0 + gr[j]) * T_) * H + gc[j] * 8);
        *(i32x4*)&xsh[0][lo[j]] = v;
    }
    BAR_LGKM();

    int* slots = cnts + g * 32;                        // 128B apart per team
    int* myslot = slots + m;
    const int* pollp = slots + l16;                    // lane-indexed slot
    const int frag_base = l16 * PITCH_US + quad * 8;   // + kk*32

    for (int t = 0; t < T_ - 1; ++t) {
        // a) issue x(t+1) prefetch (plain cached loads)
        i32x4 xv0, xv1, xv2, xv3;
        const int have_x = (t + 1 < T_ - 1);
        if (have_x) {
            xv0 = *(const i32x4*)(Xbf + ((size_t)(n0 + gr[0]) * T_ + t + 1) * H + gc[0] * 8);
            xv1 = *(const i32x4*)(Xbf + ((size_t)(n0 + gr[1]) * T_ + t + 1) * H + gc[1] * 8);
            xv2 = *(const i32x4*)(Xbf + ((size_t)(n0 + gr[2]) * T_ + t + 1) * H + gc[2] * 8);
            xv3 = *(const i32x4*)(Xbf + ((size_t)(n0 + gr[3]) * T_ + t + 1) * H + gc[3] * 8);
        }

        // b) x-part MFMA (independent of h -> overlaps the wait)
        f32x4 ax0 = {}, ax1 = {};
        {
            const ushort* xb = xsh[t & 1];
#pragma unroll
            for (int kk = 0; kk < 16; ++kk) {
                short8 b = *(const short8*)&xb[frag_base + kk * 32];
                ax0 = __builtin_amdgcn_mfma_f32_16x16x32_bf16(ax[0][kk], b, ax0, 0, 0, 0);
                ax1 = __builtin_amdgcn_mfma_f32_16x16x32_bf16(ax[1][kk], b, ax1, 0, 0, 0);
            }
        }

        // c) wait for teammates' h(t): lane l16 polls slot l16. Phase 1
        //    (loc only): sc0 reads of the local L2 where the plain-store
        //    signal lands. Phase 2: agent reads via MALL (R0-proven) —
        //    correctness net if phase 1's visibility theory is wrong.
        if (t > 0) {
            bool done = false;
            if (loc) {
                for (int it = 0; it < PH1_CAP; ++it) {
                    int v = load_slot_l2(pollp);
                    if (__all(v >= t)) { done = true; break; }
                    __builtin_amdgcn_s_sleep(1);
                }
            }
            if (!done) {
                for (int it = 0; it < POLL_CAP; ++it) {
                    int v = __hip_atomic_load(pollp, __ATOMIC_RELAXED,
                                              __HIP_MEMORY_SCOPE_AGENT);
                    if (__all(v >= t)) break;
                    __builtin_amdgcn_s_sleep(1);
                }
            }
        }

        // d) stage h(t) into LDS (16B loads; local L2 for loc teams)
        {
            const ushort* hin = (t == 0) ? h0 : ((t & 1) ? pp0 : pp1);
            const ushort* p0 = hin + (size_t)(n0 + gr[0]) * H + gc[0] * 8;
            const ushort* p1 = hin + (size_t)(n0 + gr[1]) * H + gc[1] * 8;
            const ushort* p2 = hin + (size_t)(n0 + gr[2]) * H + gc[2] * 8;
            const ushort* p3 = hin + (size_t)(n0 + gr[3]) * H + gc[3] * 8;
            i32x4 v0, v1, v2, v3;
            if (loc) { LOAD4_SC0(v0, v1, v2, v3, p0, p1, p2, p3); }
            else     { LOAD4_SC01(v0, v1, v2, v3, p0, p1, p2, p3); }
            *(i32x4*)&hsh[lo[0]] = v0;
            *(i32x4*)&hsh[lo[1]] = v1;
            *(i32x4*)&hsh[lo[2]] = v2;
            *(i32x4*)&hsh[lo[3]] = v3;
        }
        BAR_LGKM();

        // e) h-part MFMA
        f32x4 a0 = {}, a1 = {};
#pragma unroll
        for (int kk = 0; kk < 16; ++kk) {
            short8 b = *(const short8*)&hsh[frag_base + kk * 32];
            a0 = __builtin_amdgcn_mfma_f32_16x16x32_bf16(af[0][kk], b, a0, 0, 0, 0);
            a1 = __builtin_amdgcn_mfma_f32_16x16x32_bf16(af[1][kk], b, a1, 0, 0, 0);
        }

        // f) write x(t+1) into the other xsh buffer
        if (have_x) {
            ushort* xb = xsh[(t + 1) & 1];
            *(i32x4*)&xb[lo[0]] = xv0;
            *(i32x4*)&xb[lo[1]] = xv1;
            *(i32x4*)&xb[lo[2]] = xv2;
            *(i32x4*)&xb[lo[3]] = xv3;
        }

        // g) epilogue: combine, activate, update c
        float hv[4];
#pragma unroll
        for (int r = 0; r < 4; ++r) {
            float v0 = a0[r] + ax0[r], v1 = a1[r] + ax1[r];
            float p0 = __shfl_xor(v0, 32, 64);
            float p1 = __shfl_xor(v1, 32, 64);
            float iv = (quad < 2) ? v0 : p0;
            float fv = (quad < 2) ? p0 : v0;
            float gv = (quad < 2) ? v1 : p1;
            float ov = (quad < 2) ? p1 : v1;
            iv = fast_sig(iv + bgi[r]);
            fv = fast_sig(fv + bgf[r]);
            gv = fast_tanh(gv + bgg[r]);
            ov = fast_sig(ov + bgo[r]);
            float cn = fv * c[r] + iv * gv;
            c[r] = cn;
            hv[r] = ov * fast_tanh(cn);
        }

        // h) h store (exchange buffer) — the only VMEM outstanding at drain
        ushort4v o4 = { f2bf(hv[0]), f2bf(hv[1]), f2bf(hv[2]), f2bf(hv[3]) };
        ushort* hout = (t & 1) ? pp1 : pp0;
        if (quad < 2) {
            u64* hp = (u64*)(hout + (size_t)myrow * H + ccol);
            if (loc) *hp = __builtin_bit_cast(u64, o4);
            else __hip_atomic_store(hp, __builtin_bit_cast(u64, o4),
                                    __ATOMIC_RELAXED, __HIP_MEMORY_SCOPE_AGENT);
        }

        // i) drain h stores, block barrier, then signal slot m := t+1.
        //    loc: PLAIN unflagged store -> local L2 (phase-1 visibility),
        //    then agent store -> MALL (phase-2 net). Monotonic value ->
        //    no lost-wakeup; eviction/ordering races only under-report.
        BAR_ALL();
        if (tid == 0) {
            if (loc) store_slot_plain(myslot, t + 1);
            __hip_atomic_store(myslot, t + 1, __ATOMIC_RELAXED,
                               __HIP_MEMORY_SCOPE_AGENT);
        }

        // j) S store AFTER the signal — drained by a later vmcnt(0)
        if (quad < 2)
            *(ushort4v*)(S + ((size_t)myrow * T_ + (t + 1)) * H + ccol) = o4;
    }
}

// ---------------------------------------------------------------------------
// K3: phase C fused with score head.
// ---------------------------------------------------------------------------
__global__ __launch_bounds__(256) void gemm_score(
    const ushort* __restrict__ Sm, const ushort* __restrict__ Xbf,
    const ushort* __restrict__ W1T,   // [256][1024]
    const float* __restrict__ b1, const float* __restrict__ W2,
    float* __restrict__ scores)
{
    const int tid  = threadIdx.x;
    const int wave = tid >> 6, lane = tid & 63;
    const int quad = lane >> 4, l16 = lane & 15;
    const int m0 = blockIdx.y * 128 + wave * 32;
    const int n0 = blockIdx.x * 64;
    const int koff = quad * 8;

    f32x4 acc[2][4] = {};

    for (int src = 0; src < 2; ++src) {
        const ushort* A  = src ? Xbf : Sm;
        const ushort* Bm = W1T + src * 512;
        const ushort* a0p = A + (size_t)(m0 + l16) * H + koff;
        const ushort* a1p = A + (size_t)(m0 + 16 + l16) * H + koff;
        const ushort* bp  = Bm + (size_t)(n0 + l16) * 1024 + koff;
        for (int kk = 0; kk < H; kk += 32) {
            short8 a0 = *(const short8*)(a0p + kk);
            short8 a1 = *(const short8*)(a1p + kk);
#pragma unroll
            for (int nf = 0; nf < 4; ++nf) {
                short8 b = *(const short8*)(bp + (size_t)nf * 16 * 1024 + kk);
                acc[0][nf] = __builtin_amdgcn_mfma_f32_16x16x32_bf16(a0, b, acc[0][nf], 0, 0, 0);
                acc[1][nf] = __builtin_amdgcn_mfma_f32_16x16x32_bf16(a1, b, acc[1][nf], 0, 0, 0);
            }
        }
    }

    float w2v[4], b1v[4];
#pragma unroll
    for (int nf = 0; nf < 4; ++nf) {
        const int col = n0 + nf * 16 + l16;
        w2v[nf] = W2[col];
        b1v[nf] = b1[col];
    }

#pragma unroll
    for (int mf = 0; mf < 2; ++mf) {
#pragma unroll
        for (int r = 0; r < 4; ++r) {
            float p = 0.f;
#pragma unroll
            for (int nf = 0; nf < 4; ++nf)
                p += fmaxf(acc[mf][nf][r] + b1v[nf], 0.f) * w2v[nf];
            p += __shfl_xor(p, 1, 64);
            p += __shfl_xor(p, 2, 64);
            p += __shfl_xor(p, 4, 64);
            p += __shfl_xor(p, 8, 64);
            if (l16 == 0)
                atomicAdd(&scores[m0 + mf * 16 + quad * 4 + r], p);
        }
    }
}

// ---------------------------------------------------------------------------
// K4: out[b] = sum_t (scores[b*T+t] + b2)
// ---------------------------------------------------------------------------
__global__ __launch_bounds__(64) void reduce_scores(
    const float* __restrict__ scores, const float* __restrict__ b2,
    float* __restrict__ out)
{
    const int b    = blockIdx.x;
    const int lane = threadIdx.x;
    float s = scores[(size_t)b * T_ + lane] + b2[0];
#pragma unroll
    for (int off = 32; off; off >>= 1) s += __shfl_xor(s, off, 64);
    if (lane == 0) out[b] = s;
}

// ---------------------------------------------------------------------------
extern "C" void kernel_launch(void* const* d_in, const int* in_sizes, int n_in,
                              void* d_out, int out_size, void* d_ws, size_t ws_size,
                              hipStream_t stream)
{
    const float* init_state = (const float*)d_in[0];
    const float* choice_emb = (const float*)d_in[1];
    const int*   arg_seq    = (const int*)  d_in[2];
    const float* Wx         = (const float*)d_in[3];
    const float* Wh         = (const float*)d_in[4];
    const float* bg         = (const float*)d_in[5];
    const float* W1         = (const float*)d_in[6];
    const float* b1         = (const float*)d_in[7];
    const float* W2         = (const float*)d_in[8];
    const float* b2         = (const float*)d_in[9];
    float* out = (float*)d_out;

    // workspace layout
    ushort* WxT = (ushort*)d_ws;                 // [2048,512] bf16
    ushort* WhT = WxT + 1048576;                 // [2048,512] bf16
    ushort* W1T = WhT + 1048576;                 // [256,1024] bf16
    ushort* Xbf = W1T + 262144;                  // [BT,512]  bf16
    ushort* S   = Xbf + 8388608;                 // [B,T,H]   bf16
    ushort* h0  = S   + 8388608;                 // [B,H]
    ushort* pp0 = h0  + 131072;                  // [B,H]
    ushort* pp1 = pp0 + 131072;                  // [B,H]
    float*  scores  = (float*)(pp1 + 131072);    // [BT]
    int*    xcd_tbl = (int*)(scores + BT);       // [256]
    int*    cnts    = xcd_tbl + 256;             // [16*32] slot arrays

    // zero scores + table + slots (contiguous ints)
    zero_buf<<<70, 256, 0, stream>>>((int*)scores, BT + 256 + 512);

    // fused weight prep (Wx, Wh, W1 in one launch)
    prep_weights<<<2304, 256, 0, stream>>>(Wx, Wh, W1, WxT, WhT, W1T);

    // embedding gather -> bf16; state init
    gather_embed_bf16<<<BT, 128, 0, stream>>>(choice_emb, arg_seq, Xbf);
    init_prep<<<B_, 128, 0, stream>>>(init_state, h0, S);

    // Phase A+B fused: persistent recurrence with in-kernel x@Wx
    lstm_fused_main<<<256, 256, 0, stream>>>(
        WhT, WxT, Xbf, bg, init_state, h0, pp0, pp1, S, xcd_tbl, cnts);

    // Phase C+D fused: score accumulation
    gemm_score<<<dim3(C1 / 64, BT / 128), 256, 0, stream>>>(
        S, Xbf, W1T, b1, W2, scores);
    reduce_scores<<<B_, 64, 0, stream>>>(scores, b2, out);
}

// Round 5
// 394.870 us; speedup vs baseline: 2220.3047x; 2.4004x over previous
//
#include <hip/hip_runtime.h>
#include <hip/hip_bf16.h>
#include <math.h>

// Problem constants
#define H   512
#define E   512
#define B_  256
#define T_  64
#define G4  2048   // 4*H
#define C1  256    // MLP hidden
#define BT  16384  // B*T

#define SPIN_CAP (1 << 22)   // discovery spin bound (dispatch latency)
#define POLL_CAP (1 << 18)   // per-step poll/spin bound: failure -> slow-but-
                             // correct run (R2/R4-proven signature), not a hang

typedef __attribute__((ext_vector_type(8))) short  short8;   // 8 bf16 (4 VGPRs)
typedef __attribute__((ext_vector_type(4))) float  f32x4;    // MFMA acc
typedef __attribute__((ext_vector_type(4))) int    i32x4;    // 16B granule
typedef __attribute__((ext_vector_type(4))) unsigned short ushort4v;
typedef unsigned short ushort;
typedef unsigned long long u64;

// LDS tile: row-major [row][kc granule], pitch 65 granules (odd) = 520 ushorts.
#define PITCH_US 520

#define BAR_LGKM() asm volatile("s_waitcnt lgkmcnt(0)\n\ts_barrier" ::: "memory")
#define BAR_ALL()  asm volatile("s_waitcnt vmcnt(0) lgkmcnt(0)\n\ts_barrier" ::: "memory")

// ---------------------------------------------------------------------------
// Coherence ledger (R2/R3/R4 errata — measured on MI355X, this problem):
//   plain store -> sc0 load, STREAMED line:  works (R0 h-data path; consumer
//     L1 capacity-evicts between uses, re-read hits shared XCD L2).
//   plain store -> sc0 load, POLLED line:    NEVER works. sc0 does NOT bypass
//     the consumer L1 on gfx950; a polled line stays L1-resident and stale
//     forever (no cross-CU L1 invalidation). R4: burned PH1 cap every step.
//   unflagged atomic -> sc0 load:            NEVER (RMW at MALL, L2 line
//     untouched; R2: 33ms/step poll burn).
//   volatile store -> sc0 load:              NEVER (compiler emits sc0 sc1,
//     bypasses L2 to MALL; R3).
//   any store/atomic -> AGENT(sc1) load:     works (MALL truth; R0-proven).
// => Cross-CU flags MUST go through the MALL. Optimization target is the
//    VOLUME of MALL traffic, not its latency class.
// ---------------------------------------------------------------------------

__device__ __forceinline__ ushort f2bf(float x) {
    unsigned u = __builtin_bit_cast(unsigned, x);
    unsigned r = (u + 0x7FFFu + ((u >> 16) & 1u)) >> 16;
    return (ushort)r;
}
__device__ __forceinline__ float fast_sig(float x) {
    return __builtin_amdgcn_rcpf(1.f + __expf(-x));
}
__device__ __forceinline__ float fast_tanh(float x) {
    return 1.f - 2.f * __builtin_amdgcn_rcpf(1.f + __expf(2.f * x));
}

// 4x 16B loads, batched, drained. sc0: L1-bypass-to-L2 for STREAMED data
// (safe: these lines are capacity-evicted between uses; see ledger).
#define LOAD4_SC0(v0,v1,v2,v3,p0,p1,p2,p3) \
  asm volatile("global_load_dwordx4 %0, %4, off sc0\n\t" \
               "global_load_dwordx4 %1, %5, off sc0\n\t" \
               "global_load_dwordx4 %2, %6, off sc0\n\t" \
               "global_load_dwordx4 %3, %7, off sc0\n\t" \
               "s_waitcnt vmcnt(0)" \
               : "=&v"(v0), "=&v"(v1), "=&v"(v2), "=&v"(v3) \
               : "v"(p0), "v"(p1), "v"(p2), "v"(p3) : "memory")
// sc0 sc1: device-coherent (MALL) — cross-XCD fallback (R5/R8-proven).
#define LOAD4_SC01(v0,v1,v2,v3,p0,p1,p2,p3) \
  asm volatile("global_load_dwordx4 %0, %4, off sc0 sc1\n\t" \
               "global_load_dwordx4 %1, %5, off sc0 sc1\n\t" \
               "global_load_dwordx4 %2, %6, off sc0 sc1\n\t" \
               "global_load_dwordx4 %3, %7, off sc0 sc1\n\t" \
               "s_waitcnt vmcnt(0)" \
               : "=&v"(v0), "=&v"(v1), "=&v"(v2), "=&v"(v3) \
               : "v"(p0), "v"(p1), "v"(p2), "v"(p3) : "memory")

// ---------------------------------------------------------------------------
// P0: fused weight prep — transpose + cast fp32 [K][N] -> bf16 [N][K]
// ---------------------------------------------------------------------------
__global__ __launch_bounds__(256) void prep_weights(
    const float* __restrict__ Wx, const float* __restrict__ Wh,
    const float* __restrict__ W1,
    ushort* __restrict__ WxT, ushort* __restrict__ WhT, ushort* __restrict__ W1T)
{
    __shared__ float t[32][33];
    int bx = blockIdx.x;
    const float* in; ushort* out; int K, N, k0, n0;
    if (bx < 1024)       { in = Wx; out = WxT; K = 512;  N = 2048; k0 = (bx >> 6) * 32; n0 = (bx & 63) * 32; }
    else if (bx < 2048)  { bx -= 1024; in = Wh; out = WhT; K = 512;  N = 2048; k0 = (bx >> 6) * 32; n0 = (bx & 63) * 32; }
    else                 { bx -= 2048; in = W1; out = W1T; K = 1024; N = 256;  k0 = (bx >> 3) * 32; n0 = (bx & 7) * 32; }
    const int tr = threadIdx.x >> 3;
    const int tc = (threadIdx.x & 7) * 4;
    float4 v = *(const float4*)(in + (size_t)(k0 + tr) * N + n0 + tc);
    t[tr][tc + 0] = v.x; t[tr][tc + 1] = v.y; t[tr][tc + 2] = v.z; t[tr][tc + 3] = v.w;
    __syncthreads();
    ushort4v o = { f2bf(t[tc + 0][tr]), f2bf(t[tc + 1][tr]),
                   f2bf(t[tc + 2][tr]), f2bf(t[tc + 3][tr]) };
    *(ushort4v*)(out + (size_t)(n0 + tr) * K + k0 + tc) = o;
}

// ---------------------------------------------------------------------------
// P1: gather X[r,:] = bf16(choice_embed[arg_seq[r], :])
// ---------------------------------------------------------------------------
__global__ __launch_bounds__(128) void gather_embed_bf16(
    const float* __restrict__ emb, const int* __restrict__ idx,
    ushort* __restrict__ X)
{
    const int r = blockIdx.x;
    const int v = idx[r];
    const int c = threadIdx.x * 4;
    float4 f = *(const float4*)(emb + (size_t)v * E + c);
    ushort4v o = { f2bf(f.x), f2bf(f.y), f2bf(f.z), f2bf(f.w) };
    *(ushort4v*)(X + (size_t)r * E + c) = o;
}

// ---------------------------------------------------------------------------
// P2: h0 (bf16) and S[:,0,:] (bf16) from init_state
// ---------------------------------------------------------------------------
__global__ __launch_bounds__(128) void init_prep(
    const float* __restrict__ init, ushort* __restrict__ h0,
    ushort* __restrict__ S)
{
    const int r = blockIdx.x;
    const int c = threadIdx.x * 4;
    float4 f = *(const float4*)(init + (size_t)r * H + c);
    ushort4v o = { f2bf(f.x), f2bf(f.y), f2bf(f.z), f2bf(f.w) };
    *(ushort4v*)(h0 + (size_t)r * H + c) = o;
    *(ushort4v*)(S + ((size_t)r * T_) * H + c) = o;
}

// ---------------------------------------------------------------------------
// P3: zero scores + xcd table + counters (contiguous region)
// ---------------------------------------------------------------------------
__global__ __launch_bounds__(256) void zero_buf(int* p, int n) {
    int i = blockIdx.x * 256 + threadIdx.x;
    if (i < n) p[i] = 0;
}

// ---------------------------------------------------------------------------
// K2: persistent fused LSTM recurrence + fused x@Wx.
// 256 blocks, 1/CU. XCD discovery -> 16-block XCD-local teams where dispatch
// allows. Signal: ONE cumulative counter per team, device-scope atomicAdd
// (R0-proven). Poll: ONE MALL poller per block (wave 0, AGENT loads) +
// LDS-flag relay to waves 1-3 — cuts the MALL read storm on each team line
// 4x (R0: 64 pollers/line ~ one access/11cy ~ saturated; now ~44cy).
// The producer's atomicAdd RMW no longer queues behind the read storm.
// h data: sc0 local-L2 for loc teams, sc0sc1 fallback (R8-proven; safe per
// ledger — streamed lines only). S store after the signal (off the drain
// path). LDS: row-major odd-pitch tiles, conflict-free both directions.
// ---------------------------------------------------------------------------
__global__ __launch_bounds__(256, 1) void lstm_fused_main(
    const ushort* __restrict__ WhT, const ushort* __restrict__ WxT,
    const ushort* __restrict__ Xbf, const float* __restrict__ bg,
    const float*  __restrict__ init_state, const ushort* __restrict__ h0,
    ushort* __restrict__ pp0, ushort* __restrict__ pp1,
    ushort* __restrict__ S, int* __restrict__ xcd_tbl, int* __restrict__ cnts)
{
    __shared__ __align__(16) ushort hsh[16 * PITCH_US];
    __shared__ __align__(16) ushort xsh[2][16 * PITCH_US];
    __shared__ int exl[256];
    __shared__ int xflag;          // LDS relay: last step whose h(t) is ready

    const int tid  = threadIdx.x;
    const int wave = tid >> 6, lane = tid & 63;
    const int quad = lane >> 4, l16 = lane & 15;

    // ---- one-time team discovery (bounded) ----
    int xcd;
    asm volatile("s_getreg_b32 %0, hwreg(HW_REG_XCC_ID)" : "=s"(xcd));
    if (tid == 0) {
        xflag = 0;
        __hip_atomic_store(&xcd_tbl[blockIdx.x], (xcd & 7) + 1,
                           __ATOMIC_RELAXED, __HIP_MEMORY_SCOPE_AGENT);
    }
    if (wave == 0) {
        for (int it = 0; it < SPIN_CAP; ++it) {
            int miss = 0;
#pragma unroll
            for (int j = 0; j < 4; ++j) {
                int i = lane + j * 64;
                int v = __hip_atomic_load(&xcd_tbl[i], __ATOMIC_RELAXED,
                                          __HIP_MEMORY_SCOPE_AGENT);
                exl[i] = (v == 0) ? 0 : (v - 1);
                if (v == 0) miss = 1;
            }
            if (!__any(miss)) break;
            __builtin_amdgcn_s_sleep(4);
        }
    }
    BAR_LGKM();

    // deterministic assignment (identical scan in every thread)
    int g = 0, m = 0, loc = 0;
    {
        int cntx[8] = {0,0,0,0,0,0,0,0};
        for (int i = 0; i < 256; ++i) cntx[exl[i] & 7]++;
        int take[8], base[8], tA = 0;
        for (int x = 0; x < 8; ++x) {
            int tk = cntx[x] >> 4;
            if (tA + tk > 16) tk = 16 - tA;
            take[x] = tk; base[x] = tA; tA += tk;
        }
        int rc[8] = {0,0,0,0,0,0,0,0}, lc = 0;
        for (int i = 0; i < 256; ++i) {
            int x = exl[i] & 7, r = rc[x]++;
            if ((r >> 4) < take[x]) {
                if (i == (int)blockIdx.x) { g = base[x] + (r >> 4); m = r & 15; loc = 1; }
            } else {
                if (i == (int)blockIdx.x) { g = tA + (lc >> 4); m = lc & 15; loc = 0; }
                lc++;
            }
        }
    }

    const int n0   = g * 16;
    const int jw   = m * 32 + wave * 8;
    const int koff = quad * 8;
    const int ccol = jw + (quad & 1) * 4;
    const int myrow = n0 + l16;

    // A-frag preloads: Wh and Wx (layout validated rounds 2-8)
    short8 af[2][16], ax[2][16];
#pragma unroll
    for (int mf = 0; mf < 2; ++mf) {
        const int gate = mf * 2 + (l16 >> 3);
        const size_t rowoff = (size_t)(gate * 512 + jw + (l16 & 7)) * 512 + koff;
        const ushort* bh = WhT + rowoff;
        const ushort* bx = WxT + rowoff;
#pragma unroll
        for (int kk = 0; kk < 16; ++kk) {
            af[mf][kk] = *(const short8*)(bh + kk * 32);
            ax[mf][kk] = *(const short8*)(bx + kk * 32);
        }
    }

    // bias preload
    float bgi[4], bgf[4], bgg[4], bgo[4];
#pragma unroll
    for (int r = 0; r < 4; ++r) {
        bgi[r] = bg[ccol + r];
        bgf[r] = bg[512 + ccol + r];
        bgg[r] = bg[1024 + ccol + r];
        bgo[r] = bg[1536 + ccol + r];
    }

    // c-state init
    float c[4];
    {
        const float* ip = init_state + (size_t)myrow * H + ccol;
#pragma unroll
        for (int r = 0; r < 4; ++r) c[r] = ip[r];
    }

    // staging coords: 4 granules of 16B per thread; row-major pitch-520 tile
    int gr[4], gc[4], lo[4];
#pragma unroll
    for (int j = 0; j < 4; ++j) {
        int lin = tid + j * 256;
        gr[j] = lin >> 6; gc[j] = lin & 63;
        lo[j] = gr[j] * PITCH_US + gc[j] * 8;
    }

    // stage x(0) into xsh[0]
#pragma unroll
    for (int j = 0; j < 4; ++j) {
        i32x4 v = *(const i32x4*)(Xbf + ((size_t)(n0 + gr[j]) * T_) * H + gc[j] * 8);
        *(i32x4*)&xsh[0][lo[j]] = v;
    }
    BAR_LGKM();

    int* cnt = cnts + g * 32;                          // 128B apart per team
    const int frag_base = l16 * PITCH_US + quad * 8;   // + kk*32

    for (int t = 0; t < T_ - 1; ++t) {
        // a) issue x(t+1) prefetch (plain cached loads)
        i32x4 xv0, xv1, xv2, xv3;
        const int have_x = (t + 1 < T_ - 1);
        if (have_x) {
            xv0 = *(const i32x4*)(Xbf + ((size_t)(n0 + gr[0]) * T_ + t + 1) * H + gc[0] * 8);
            xv1 = *(const i32x4*)(Xbf + ((size_t)(n0 + gr[1]) * T_ + t + 1) * H + gc[1] * 8);
            xv2 = *(const i32x4*)(Xbf + ((size_t)(n0 + gr[2]) * T_ + t + 1) * H + gc[2] * 8);
            xv3 = *(const i32x4*)(Xbf + ((size_t)(n0 + gr[3]) * T_ + t + 1) * H + gc[3] * 8);
        }

        // b) x-part MFMA (independent of h -> overlaps signal travel)
        f32x4 ax0 = {}, ax1 = {};
        {
            const ushort* xb = xsh[t & 1];
#pragma unroll
            for (int kk = 0; kk < 16; ++kk) {
                short8 b = *(const short8*)&xb[frag_base + kk * 32];
                ax0 = __builtin_amdgcn_mfma_f32_16x16x32_bf16(ax[0][kk], b, ax0, 0, 0, 0);
                ax1 = __builtin_amdgcn_mfma_f32_16x16x32_bf16(ax[1][kk], b, ax1, 0, 0, 0);
            }
        }

        // c) wait for teammates' h(t): wave 0 is the block's ONLY MALL
        //    poller (AGENT loads, R0-proven pairing with the atomicAdd
        //    signal); it releases waves 1-3 through an LDS flag (monotonic
        //    step value -> no lost wakeup; ds_read spin, zero fabric
        //    traffic). 4x fewer MALL accesses per team line than R0.
        if (t > 0) {
            if (wave == 0) {
                const int tgt = t << 4;
                for (int it = 0; it < POLL_CAP; ++it) {
                    if (__hip_atomic_load(cnt, __ATOMIC_RELAXED,
                                          __HIP_MEMORY_SCOPE_AGENT) >= tgt) break;
                    __builtin_amdgcn_s_sleep(1);
                }
                if (lane == 0) *(volatile int*)&xflag = t;
            } else {
                for (int it = 0; it < POLL_CAP; ++it) {
                    if (*(volatile int*)&xflag >= t) break;
                    __builtin_amdgcn_s_sleep(1);
                }
            }
        }

        // d) stage h(t) into LDS (16B loads; local L2 for loc teams)
        {
            const ushort* hin = (t == 0) ? h0 : ((t & 1) ? pp0 : pp1);
            const ushort* p0 = hin + (size_t)(n0 + gr[0]) * H + gc[0] * 8;
            const ushort* p1 = hin + (size_t)(n0 + gr[1]) * H + gc[1] * 8;
            const ushort* p2 = hin + (size_t)(n0 + gr[2]) * H + gc[2] * 8;
            const ushort* p3 = hin + (size_t)(n0 + gr[3]) * H + gc[3] * 8;
            i32x4 v0, v1, v2, v3;
            if (loc) { LOAD4_SC0(v0, v1, v2, v3, p0, p1, p2, p3); }
            else     { LOAD4_SC01(v0, v1, v2, v3, p0, p1, p2, p3); }
            *(i32x4*)&hsh[lo[0]] = v0;
            *(i32x4*)&hsh[lo[1]] = v1;
            *(i32x4*)&hsh[lo[2]] = v2;
            *(i32x4*)&hsh[lo[3]] = v3;
        }
        BAR_LGKM();

        // e) h-part MFMA
        f32x4 a0 = {}, a1 = {};
#pragma unroll
        for (int kk = 0; kk < 16; ++kk) {
            short8 b = *(const short8*)&hsh[frag_base + kk * 32];
            a0 = __builtin_amdgcn_mfma_f32_16x16x32_bf16(af[0][kk], b, a0, 0, 0, 0);
            a1 = __builtin_amdgcn_mfma_f32_16x16x32_bf16(af[1][kk], b, a1, 0, 0, 0);
        }

        // f) write x(t+1) into the other xsh buffer
        if (have_x) {
            ushort* xb = xsh[(t + 1) & 1];
            *(i32x4*)&xb[lo[0]] = xv0;
            *(i32x4*)&xb[lo[1]] = xv1;
            *(i32x4*)&xb[lo[2]] = xv2;
            *(i32x4*)&xb[lo[3]] = xv3;
        }

        // g) epilogue: combine, activate, update c
        float hv[4];
#pragma unroll
        for (int r = 0; r < 4; ++r) {
            float v0 = a0[r] + ax0[r], v1 = a1[r] + ax1[r];
            float p0 = __shfl_xor(v0, 32, 64);
            float p1 = __shfl_xor(v1, 32, 64);
            float iv = (quad < 2) ? v0 : p0;
            float fv = (quad < 2) ? p0 : v0;
            float gv = (quad < 2) ? v1 : p1;
            float ov = (quad < 2) ? p1 : v1;
            iv = fast_sig(iv + bgi[r]);
            fv = fast_sig(fv + bgf[r]);
            gv = fast_tanh(gv + bgg[r]);
            ov = fast_sig(ov + bgo[r]);
            float cn = fv * c[r] + iv * gv;
            c[r] = cn;
            hv[r] = ov * fast_tanh(cn);
        }

        // h) h store (exchange buffer) — the only VMEM outstanding at drain
        ushort4v o4 = { f2bf(hv[0]), f2bf(hv[1]), f2bf(hv[2]), f2bf(hv[3]) };
        ushort* hout = (t & 1) ? pp1 : pp0;
        if (quad < 2) {
            u64* hp = (u64*)(hout + (size_t)myrow * H + ccol);
            if (loc) *hp = __builtin_bit_cast(u64, o4);
            else __hip_atomic_store(hp, __builtin_bit_cast(u64, o4),
                                    __ATOMIC_RELAXED, __HIP_MEMORY_SCOPE_AGENT);
        }

        // i) drain h store, block barrier, signal via device-scope atomic
        BAR_ALL();
        if (tid == 0) atomicAdd(cnt, 1);

        // j) S store AFTER the signal — drained by a later vmcnt(0)
        if (quad < 2)
            *(ushort4v*)(S + ((size_t)myrow * T_ + (t + 1)) * H + ccol) = o4;
    }
}

// ---------------------------------------------------------------------------
// K3: phase C fused with score head.
// ---------------------------------------------------------------------------
__global__ __launch_bounds__(256) void gemm_score(
    const ushort* __restrict__ Sm, const ushort* __restrict__ Xbf,
    const ushort* __restrict__ W1T,   // [256][1024]
    const float* __restrict__ b1, const float* __restrict__ W2,
    float* __restrict__ scores)
{
    const int tid  = threadIdx.x;
    const int wave = tid >> 6, lane = tid & 63;
    const int quad = lane >> 4, l16 = lane & 15;
    const int m0 = blockIdx.y * 128 + wave * 32;
    const int n0 = blockIdx.x * 64;
    const int koff = quad * 8;

    f32x4 acc[2][4] = {};

    for (int src = 0; src < 2; ++src) {
        const ushort* A  = src ? Xbf : Sm;
        const ushort* Bm = W1T + src * 512;
        const ushort* a0p = A + (size_t)(m0 + l16) * H + koff;
        const ushort* a1p = A + (size_t)(m0 + 16 + l16) * H + koff;
        const ushort* bp  = Bm + (size_t)(n0 + l16) * 1024 + koff;
        for (int kk = 0; kk < H; kk += 32) {
            short8 a0 = *(const short8*)(a0p + kk);
            short8 a1 = *(const short8*)(a1p + kk);
#pragma unroll
            for (int nf = 0; nf < 4; ++nf) {
                short8 b = *(const short8*)(bp + (size_t)nf * 16 * 1024 + kk);
                acc[0][nf] = __builtin_amdgcn_mfma_f32_16x16x32_bf16(a0, b, acc[0][nf], 0, 0, 0);
                acc[1][nf] = __builtin_amdgcn_mfma_f32_16x16x32_bf16(a1, b, acc[1][nf], 0, 0, 0);
            }
        }
    }

    float w2v[4], b1v[4];
#pragma unroll
    for (int nf = 0; nf < 4; ++nf) {
        const int col = n0 + nf * 16 + l16;
        w2v[nf] = W2[col];
        b1v[nf] = b1[col];
    }

#pragma unroll
    for (int mf = 0; mf < 2; ++mf) {
#pragma unroll
        for (int r = 0; r < 4; ++r) {
            float p = 0.f;
#pragma unroll
            for (int nf = 0; nf < 4; ++nf)
                p += fmaxf(acc[mf][nf][r] + b1v[nf], 0.f) * w2v[nf];
            p += __shfl_xor(p, 1, 64);
            p += __shfl_xor(p, 2, 64);
            p += __shfl_xor(p, 4, 64);
            p += __shfl_xor(p, 8, 64);
            if (l16 == 0)
                atomicAdd(&scores[m0 + mf * 16 + quad * 4 + r], p);
        }
    }
}

// ---------------------------------------------------------------------------
// K4: out[b] = sum_t (scores[b*T+t] + b2)
// ---------------------------------------------------------------------------
__global__ __launch_bounds__(64) void reduce_scores(
    const float* __restrict__ scores, const float* __restrict__ b2,
    float* __restrict__ out)
{
    const int b    = blockIdx.x;
    const int lane = threadIdx.x;
    float s = scores[(size_t)b * T_ + lane] + b2[0];
#pragma unroll
    for (int off = 32; off; off >>= 1) s += __shfl_xor(s, off, 64);
    if (lane == 0) out[b] = s;
}

// ---------------------------------------------------------------------------
extern "C" void kernel_launch(void* const* d_in, const int* in_sizes, int n_in,
                              void* d_out, int out_size, void* d_ws, size_t ws_size,
                              hipStream_t stream)
{
    const float* init_state = (const float*)d_in[0];
    const float* choice_emb = (const float*)d_in[1];
    const int*   arg_seq    = (const int*)  d_in[2];
    const float* Wx         = (const float*)d_in[3];
    const float* Wh         = (const float*)d_in[4];
    const float* bg         = (const float*)d_in[5];
    const float* W1         = (const float*)d_in[6];
    const float* b1         = (const float*)d_in[7];
    const float* W2         = (const float*)d_in[8];
    const float* b2         = (const float*)d_in[9];
    float* out = (float*)d_out;

    // workspace layout
    ushort* WxT = (ushort*)d_ws;                 // [2048,512] bf16
    ushort* WhT = WxT + 1048576;                 // [2048,512] bf16
    ushort* W1T = WhT + 1048576;                 // [256,1024] bf16
    ushort* Xbf = W1T + 262144;                  // [BT,512]  bf16
    ushort* S   = Xbf + 8388608;                 // [B,T,H]   bf16
    ushort* h0  = S   + 8388608;                 // [B,H]
    ushort* pp0 = h0  + 131072;                  // [B,H]
    ushort* pp1 = pp0 + 131072;                  // [B,H]
    float*  scores  = (float*)(pp1 + 131072);    // [BT]
    int*    xcd_tbl = (int*)(scores + BT);       // [256]
    int*    cnts    = xcd_tbl + 256;             // [16*32]

    // zero scores + table + counters (contiguous ints)
    zero_buf<<<70, 256, 0, stream>>>((int*)scores, BT + 256 + 512);

    // fused weight prep (Wx, Wh, W1 in one launch)
    prep_weights<<<2304, 256, 0, stream>>>(Wx, Wh, W1, WxT, WhT, W1T);

    // embedding gather -> bf16; state init
    gather_embed_bf16<<<BT, 128, 0, stream>>>(choice_emb, arg_seq, Xbf);
    init_prep<<<B_, 128, 0, stream>>>(init_state, h0, S);

    // Phase A+B fused: persistent recurrence with in-kernel x@Wx
    lstm_fused_main<<<256, 256, 0, stream>>>(
        WhT, WxT, Xbf, bg, init_state, h0, pp0, pp1, S, xcd_tbl, cnts);

    // Phase C+D fused: score accumulation
    gemm_score<<<dim3(C1 / 64, BT / 128), 256, 0, stream>>>(
        S, Xbf, W1T, b1, W2, scores);
    reduce_scores<<<B_, 64, 0, stream>>>(scores, b2, out);
}